// Round 1
// 340.984 us; speedup vs baseline: 1.0095x; 1.0095x over previous
//
#include <hip/hip_runtime.h>
#include <math.h>

#define H 1024
#define NH 16
#define HD 64
#define B_ 4
#define S_ 2048
#define ROWS (B_*S_)   // 8192

// -0.125 * log2(e): folded into Qh so sigmoid(s*0.125) = rcp(1 + exp2(dot))
#define QSCALE (-0.1803368801111664f)
#define ROPE_C (9.210340371976184f / 32.0f)   // ln(10000)/32

typedef __bf16 bf16x2_t __attribute__((ext_vector_type(2)));
typedef __bf16 bf16x4_t __attribute__((ext_vector_type(4)));
typedef __bf16 bf16x8_t __attribute__((ext_vector_type(8)));
typedef float floatx4_t __attribute__((ext_vector_type(4)));
typedef float floatx16_t __attribute__((ext_vector_type(16)));

// async global->LDS, 16B per lane, dest = wave-uniform base + lane*16
#define GLOAD_LDS16(gp, lp)                                                        \
    __builtin_amdgcn_global_load_lds(                                              \
        (const __attribute__((address_space(1))) unsigned int*)(gp),               \
        (__attribute__((address_space(3))) unsigned int*)(lp), 16, 0, 0)

// ---------------------------------------------------------------------------
// Fused prep: x->bf16 copy, Wp transpose+cvt, Wt transpose+cvt (one dispatch)
// ---------------------------------------------------------------------------
__global__ __launch_bounds__(256)
void prep_kernel(const float* __restrict__ x, const float* __restrict__ Wp,
                 const float* __restrict__ Wt,
                 __bf16* __restrict__ Ax, __bf16* __restrict__ Wp_t,
                 __bf16* __restrict__ Wt_t)
{
    __shared__ __bf16 t[32][33];
    const int flat = blockIdx.x;
    const int tid = threadIdx.x;

    if (flat < 8192) {
        size_t i = (size_t)flat * 256 + tid;
        float4 v = *reinterpret_cast<const float4*>(&x[i * 4]);
        bf16x4_t w = { (__bf16)v.x, (__bf16)v.y, (__bf16)v.z, (__bf16)v.w };
        *reinterpret_cast<bf16x4_t*>(&Ax[i * 4]) = w;
        return;
    }
    const float* W; __bf16* Wo; int K, N, bn, bk;
    if (flat < 12288) {
        int id = flat - 8192;  W = Wp; Wo = Wp_t; K = 1024; N = 4096;
        bn = (id & 127) * 32;  bk = (id >> 7) * 32;
    } else {
        int id = flat - 12288; W = Wt; Wo = Wt_t; K = 1024; N = 1024;
        bn = (id & 31) * 32;   bk = (id >> 5) * 32;
    }
    const int tx = tid & 31, ty = tid >> 5;
#pragma unroll
    for (int i = 0; i < 4; i++) {
        int r = ty + i * 8;
        t[tx][r] = (__bf16)W[(size_t)(bk + r) * N + bn + tx];
    }
    __syncthreads();
#pragma unroll
    for (int i = 0; i < 4; i++) {
        int r = ty + i * 8;
        Wo[(size_t)(bn + r) * K + bk + tx] = t[r][tx];
    }
}

// ===========================================================================
// gemm_proj: 256x256 tile, BK=64, 8 waves (2M x 4N), 8-phase HK schedule
// (T2 swizzle + T3/T4 counted-vmcnt + T5 setprio), 16x16x32 MFMA.
//
// LDS ring (128 KiB): A slots [buf][khalf] 4 x 16KB (256 rows x 32 k bf16),
// then B slots likewise at +64KB. Phase p (0..7): buf=p>>2, sub=p&3,
// mh=sub&1 (m-frag half), kk=sub>>1 (k-half slot).
//   reads:  bfr[0..3] at sub 0/2 (kk slot); af[0..3] (mh half) every phase
//   stage (one half-tile, 2 x global_load_lds/thread), targets:
//     p0: A[1][1] <- T+1 | p1: B[0][0] <- T+2 | p2: A[0][0] <- T+2
//     p3: B[0][1] <- T+2 | p4: A[0][1] <- T+2 | p5: B[1][0] <- T+3
//     p6: A[1][0] <- T+3 | p7: B[1][1] <- T+3        (T = 2*iter)
//   waits: vmcnt(6) after stage at p3 and p7 only (3 half-tiles in flight).
// Verified ring: each stage phi_s has a wait phi_w with phi_s+3 <= phi_w
// <= phi_read-1; each overwrite issues >= 1 end-barrier after last read.
// Swizzle: data chunk c of row r stored at linear chunk c ^ ((r>>1)&3)
// (inverse-permuted GLOBAL source, linear LDS dest per m104/m173); reads
// land on 8 distinct 16B slots per 8 rows -> 2-way (free).
// C/D layout 16x16 (m89/m91): col=lane&15, row=(lane>>4)*4+reg.
// ===========================================================================

#define MIN15(x) ((x) < 15 ? (x) : 15)

#define STAGE_A(buf, h, tile) do { int _kb = (tile) * 64 + (h) * 32;               \
        char* _lb = lwA + ((buf) * 2 + (h)) * 16384;                               \
        GLOAD_LDS16(a_src0 + _kb, _lb);                                            \
        GLOAD_LDS16(a_src1 + _kb, _lb + 1024); } while (0)
#define STAGE_B(buf, h, tile) do { int _kb = (tile) * 64 + (h) * 32;               \
        char* _lb = lwB + ((buf) * 2 + (h)) * 16384;                               \
        GLOAD_LDS16(b_src0 + _kb, _lb);                                            \
        GLOAD_LDS16(b_src1 + _kb, _lb + 1024); } while (0)

__global__ __launch_bounds__(512, 2)
void gemm_proj(const __bf16* __restrict__ A, const __bf16* __restrict__ Bt,
               const float* __restrict__ bias,
               __bf16* __restrict__ Ug, __bf16* __restrict__ Vh,
               __bf16* __restrict__ Qh, __bf16* __restrict__ Kh)
{
    __shared__ __attribute__((aligned(16))) char smem[131072];

    const int tid  = threadIdx.x;
    const int wave = tid >> 6, lane = tid & 63;
    const int ln15 = lane & 15, q4 = lane >> 4;
    const int wm = wave & 1, wn = wave >> 1;
    const int m0 = blockIdx.y * 256, n0 = blockIdx.x * 256;

    // ---- staging constants: linear LDS dest, inverse-swizzled global src ----
    const int srow0 = wave * 32 + (lane >> 2);            // row for load p=0
    const int csrc  = (lane & 3) ^ ((lane >> 3) & 3);     // swizzled 16B chunk
    const __bf16* a_src0 = A  + (size_t)(m0 + srow0) * 1024 + csrc * 8;
    const __bf16* a_src1 = a_src0 + (size_t)16 * 1024;    // row +16 (load p=1)
    const __bf16* b_src0 = Bt + (size_t)(n0 + srow0) * 1024 + csrc * 8;
    const __bf16* b_src1 = b_src0 + (size_t)16 * 1024;
    char* lwA = smem + wave * 2048;                       // + slot*16384
    char* lwB = smem + 65536 + wave * 2048;

    // ---- fragment read offsets (swizzled; s(row) = (ln15>>1)&3 since frag
    //      row bases are multiples of 16) ----
    const int sl = (ln15 >> 1) & 3;
    const int a_lane = (wm * 128 + ln15) * 64 + ((q4 ^ sl) << 4);
    const int b_lane = (wn * 64  + ln15) * 64 + ((q4 ^ sl) << 4);

    floatx4_t acc[8][4];
#pragma unroll
    for (int i = 0; i < 8; i++)
#pragma unroll
        for (int j = 0; j < 4; j++) acc[i][j] = (floatx4_t){0.f, 0.f, 0.f, 0.f};

    // ---- prologue: T0 all 4 halves + T1 {Bk0, Ak0, Bk1}, FIFO order ----
    STAGE_B(0, 0, 0); STAGE_A(0, 0, 0); STAGE_B(0, 1, 0); STAGE_A(0, 1, 0);
    STAGE_B(1, 0, 1); STAGE_A(1, 0, 1); STAGE_B(1, 1, 1);
    asm volatile("s_waitcnt vmcnt(6)" ::: "memory");   // T0 landed
    __builtin_amdgcn_s_barrier();

    bf16x8_t bfr[4];

    for (int it = 0; it < 8; ++it) {
        const int T = 2 * it;
#pragma unroll
        for (int p = 0; p < 8; ++p) {
            const int buf = p >> 2, sub = p & 3, mh = sub & 1, kk = sub >> 1;
            const char* asl = smem + (buf * 2 + kk) * 16384;
            const char* bsl = smem + 65536 + (buf * 2 + kk) * 16384;

            // ds-loads for this phase
            if ((sub & 1) == 0) {
#pragma unroll
                for (int nf = 0; nf < 4; nf++)
                    bfr[nf] = *reinterpret_cast<const bf16x8_t*>(bsl + b_lane + nf * 1024);
            }
            bf16x8_t af[4];
#pragma unroll
            for (int mfi = 0; mfi < 4; mfi++)
                af[mfi] = *reinterpret_cast<const bf16x8_t*>(asl + a_lane + (mh * 4 + mfi) * 1024);

            // stage one half-tile (dummy re-stage of tile 15 past the end:
            // those slots are never read again, keeps vmcnt counts uniform)
            if      (p == 0) STAGE_A(1, 1, MIN15(T + 1));
            else if (p == 1) STAGE_B(0, 0, MIN15(T + 2));
            else if (p == 2) STAGE_A(0, 0, MIN15(T + 2));
            else if (p == 3) STAGE_B(0, 1, MIN15(T + 2));
            else if (p == 4) STAGE_A(0, 1, MIN15(T + 2));
            else if (p == 5) STAGE_B(1, 0, MIN15(T + 3));
            else if (p == 6) STAGE_A(1, 0, MIN15(T + 3));
            else             STAGE_B(1, 1, MIN15(T + 3));

            if (p == 3 || p == 7)
                asm volatile("s_waitcnt vmcnt(6)" ::: "memory");
            __builtin_amdgcn_s_barrier();

            __builtin_amdgcn_s_setprio(1);
#pragma unroll
            for (int nf = 0; nf < 4; nf++)
#pragma unroll
                for (int mfi = 0; mfi < 4; mfi++)
                    acc[mh * 4 + mfi][nf] = __builtin_amdgcn_mfma_f32_16x16x32_bf16(
                        af[mfi], bfr[nf], acc[mh * 4 + mfi][nf], 0, 0, 0);
            __builtin_amdgcn_s_setprio(0);
            __builtin_amdgcn_s_barrier();
        }
    }
    // drain staging queue before endpgm/epilogue (pending LDS writes)
    asm volatile("s_waitcnt vmcnt(0)" ::: "memory");

    // ---- split epilogue (block-uniform region branch) ----
    const int colbase = n0 + wn * 64;
    float bv[4];
#pragma unroll
    for (int nf = 0; nf < 4; nf++) bv[nf] = bias[colbase + nf * 16 + ln15];

    const int rowb = m0 + wm * 128 + q4 * 4;   // + mf*16 + reg

    if (n0 < 1024) {
#pragma unroll
        for (int mf = 0; mf < 8; mf++)
#pragma unroll
            for (int nf = 0; nf < 4; nf++) {
                int col = colbase + nf * 16 + ln15;
#pragma unroll
                for (int reg = 0; reg < 4; reg++) {
                    int row = rowb + mf * 16 + reg;
                    Ug[(size_t)row * 1024 + col] = (__bf16)(acc[mf][nf][reg] + bv[nf]);
                }
            }
    } else if (n0 < 2048) {
        const int h = ((n0 - 1024) >> 6) + wn;    // wave spans one head
#pragma unroll
        for (int mf = 0; mf < 8; mf++)
#pragma unroll
            for (int reg = 0; reg < 4; reg++) {
                int row = rowb + mf * 16 + reg;
                int b = row >> 11, s = row & (S_ - 1);
                size_t orow = ((size_t)(b * NH + h) * S_ + s) * 64;
#pragma unroll
                for (int nf = 0; nf < 4; nf++)
                    Vh[orow + nf * 16 + ln15] = (__bf16)(acc[mf][nf][reg] + bv[nf]);
            }
    } else {
        const bool isQ = (n0 < 3072);
        const int h = ((n0 - (isQ ? 2048 : 3072)) >> 6) + wn;
        __bf16* dst = isQ ? Qh : Kh;
        const float sc = isQ ? QSCALE : 1.0f;
        // RoPE pair (d, d+32): d = nf*16+ln15 (nf=0,1), hi partner nf+2
        float inv[2];
        inv[0] = __expf(-(float)(ln15)      * ROPE_C);
        inv[1] = __expf(-(float)(16 + ln15) * ROPE_C);
#pragma unroll
        for (int mf = 0; mf < 8; mf++)
#pragma unroll
            for (int reg = 0; reg < 4; reg++) {
                int row = rowb + mf * 16 + reg;
                int b = row >> 11, s = row & (S_ - 1);
                size_t orow = ((size_t)(b * NH + h) * S_ + s) * 64;
#pragma unroll
                for (int nf = 0; nf < 2; nf++) {
                    float sn, cs;
                    __sincosf((float)s * inv[nf], &sn, &cs);
                    float lo = acc[mf][nf][reg]     + bv[nf];
                    float hi = acc[mf][nf + 2][reg] + bv[nf + 2];
                    int d = nf * 16 + ln15;
                    dst[orow + d]      = (__bf16)((lo * cs - hi * sn) * sc);
                    dst[orow + 32 + d] = (__bf16)((hi * cs + lo * sn) * sc);
                }
            }
    }
}

// ---------------------------------------------------------------------------
// out-proj GEMM: C = A @ Bt^T + bias + resid (fp32 out). 128x128 tile, m97
// structure (kept: N=1024 -> 256-tile would launch only 128 blocks).
// ---------------------------------------------------------------------------
__global__ __launch_bounds__(256)
void gemm_out(const __bf16* __restrict__ A, const __bf16* __restrict__ Bt,
              const float* __restrict__ bias, const float* __restrict__ resid,
              float* __restrict__ C, int M, int N, int K)
{
    __shared__ __bf16 As[128 * 32];
    __shared__ __bf16 Bs[128 * 32];

    const int tid  = threadIdx.x;
    const int wave = tid >> 6, lane = tid & 63;
    const int l31 = lane & 31, half = lane >> 5;
    const int wm = wave & 1, wn = wave >> 1;
    const int m0 = blockIdx.y * 128, n0 = blockIdx.x * 128;

    const int srow = lane >> 2;
    const int skc  = (((lane & 3) ^ ((srow >> 1) & 3)) * 8);

    const int fsw = (l31 >> 1) & 3;
    int aoff[2][2], boff[2][2];
#pragma unroll
    for (int mt = 0; mt < 2; mt++)
#pragma unroll
        for (int ks = 0; ks < 2; ks++) {
            int ra = wm * 64 + mt * 32 + l31;
            int rb = wn * 64 + mt * 32 + l31;
            int c = ks * 2 + half;
            aoff[mt][ks] = ra * 32 + ((c ^ fsw) * 8);
            boff[mt][ks] = rb * 32 + ((c ^ fsw) * 8);
        }

    floatx16_t acc[2][2];
#pragma unroll
    for (int i = 0; i < 2; i++)
#pragma unroll
        for (int j = 0; j < 2; j++) acc[i][j] = (floatx16_t)(0.f);

    for (int k0 = 0; k0 < K; k0 += 32) {
#pragma unroll
        for (int p = 0; p < 2; p++) {
            int i = wave * 2 + p;
            int rl = i * 16 + srow;
            GLOAD_LDS16(A  + (size_t)(m0 + rl) * K + k0 + skc, &As[i * 512]);
            GLOAD_LDS16(Bt + (size_t)(n0 + rl) * K + k0 + skc, &Bs[i * 512]);
        }
        __syncthreads();

        bf16x8_t af[2][2], bf[2][2];
#pragma unroll
        for (int mt = 0; mt < 2; mt++)
#pragma unroll
            for (int ks = 0; ks < 2; ks++) {
                af[mt][ks] = *reinterpret_cast<const bf16x8_t*>(&As[aoff[mt][ks]]);
                bf[mt][ks] = *reinterpret_cast<const bf16x8_t*>(&Bs[boff[mt][ks]]);
            }
#pragma unroll
        for (int ks = 0; ks < 2; ks++)
#pragma unroll
            for (int mt = 0; mt < 2; mt++)
#pragma unroll
                for (int nt = 0; nt < 2; nt++)
                    acc[mt][nt] = __builtin_amdgcn_mfma_f32_32x32x16_bf16(
                        af[mt][ks], bf[nt][ks], acc[mt][nt], 0, 0, 0);
        __syncthreads();
    }

#pragma unroll
    for (int mt = 0; mt < 2; mt++) {
#pragma unroll
        for (int nt = 0; nt < 2; nt++) {
            int col = n0 + wn * 64 + nt * 32 + l31;
            float bv = bias[col];
#pragma unroll
            for (int reg = 0; reg < 16; reg++) {
                int rowf = (reg & 3) + 8 * (reg >> 2) + 4 * half;
                int row = m0 + wm * 64 + mt * 32 + rowf;
                C[(size_t)row * N + col] = acc[mt][nt][reg] + bv + resid[(size_t)row * N + col];
            }
        }
    }
}

// ---------------------------------------------------------------------------
// V transpose: Vh[bh][s][64] -> VtG[bh][d][S]
// ---------------------------------------------------------------------------
__global__ __launch_bounds__(256)
void transpose_v(const __bf16* __restrict__ Vh, __bf16* __restrict__ VtG)
{
    const int tid = threadIdx.x;
    const int st = blockIdx.x, bh = blockIdx.y;
    const int s0 = st * 64;
    const int d = tid & 63, k16 = tid >> 6;
    __bf16 vals[16];
#pragma unroll
    for (int j = 0; j < 16; j++) {
        int k = s0 + k16 * 16 + j;
        vals[j] = Vh[((size_t)bh * S_ + k) * 64 + d];
    }
    size_t orow = ((size_t)(bh * 64 + d)) * S_ + s0 + k16 * 16;
    *reinterpret_cast<bf16x8_t*>(&VtG[orow])     = *reinterpret_cast<bf16x8_t*>(&vals[0]);
    *reinterpret_cast<bf16x8_t*>(&VtG[orow + 8]) = *reinterpret_cast<bf16x8_t*>(&vals[8]);
}

// ---------------------------------------------------------------------------
// Sigmoid attention, causal, bf16 MFMA. 128 q-rows/block, S^T=K*Q^T trick,
// XOR-swizzled LDS, ping-pong K/V buffers (ONE barrier/iter).
// ---------------------------------------------------------------------------
__global__ __launch_bounds__(256)
void attn_mfma(const __bf16* __restrict__ Qh, const __bf16* __restrict__ Kh,
               const __bf16* __restrict__ VtG, __bf16* __restrict__ attn_out)
{
    __shared__ __bf16 Ks[2][4096];     // 64x64 K[k][d], swizzled
    __shared__ __bf16 Vt[2][4096];     // 64x64 V^T[d][k], swizzled
    __shared__ __bf16 Ps[4][16][72];   // per-wave P strip (reused per subtile)

    const int tid = threadIdx.x, wave = tid >> 6, lane = tid & 63;
    const int quad = lane >> 4, ln = lane & 15;
    const int qt = (S_ / 128 - 1) - (blockIdx.x >> 6);   // longest-first
    const int hb = blockIdx.x & 63, h = hb & 15, b = hb >> 4, bh = b * NH + h;
    const int Q0 = qt * 128, T0 = 2 * qt;
    const int wl = wave * 16 + ln;

    // Q fragments: loop-invariant, direct from global (2 subtiles x K=64)
    const size_t qr = ((size_t)bh * S_ + Q0 + wl) * 64;
    bf16x8_t qa[2][2];
    qa[0][0] = *reinterpret_cast<const bf16x8_t*>(&Qh[qr + quad * 8]);
    qa[0][1] = *reinterpret_cast<const bf16x8_t*>(&Qh[qr + 32 + quad * 8]);
    qa[1][0] = *reinterpret_cast<const bf16x8_t*>(&Qh[qr + 4096 + quad * 8]);
    qa[1][1] = *reinterpret_cast<const bf16x8_t*>(&Qh[qr + 4096 + 32 + quad * 8]);

    // staging lane constants (XOR swizzle)
    const int sr = lane >> 3, scl = (lane & 7) ^ sr;
    const int c0 = wave * 2, c1 = c0 + 1;                 // 1KB chunks
    const size_t khead = (size_t)bh * S_ * 64;
    const int koff0 = (c0 * 8 + sr) * 64 + scl * 8;
    const int koff1 = (c1 * 8 + sr) * 64 + scl * 8;
    const size_t vg0 = ((size_t)bh * 64 + c0 * 8 + sr) * S_ + scl * 8;
    const size_t vg1 = ((size_t)bh * 64 + c1 * 8 + sr) * S_ + scl * 8;

    // fragment LDS element offsets (kt-invariant, swizzled)
    const int m7 = ln & 7;
    int ka[4][2];
#pragma unroll
    for (int nt = 0; nt < 4; nt++) {
        int row = nt * 16 + ln;
        ka[nt][0] = row * 64 + ((quad ^ m7) << 3);
        ka[nt][1] = row * 64 + (((quad + 4) ^ m7) << 3);
    }

    floatx4_t o[2][4];
#pragma unroll
    for (int s = 0; s < 2; s++)
#pragma unroll
        for (int dt = 0; dt < 4; dt++) o[s][dt] = (floatx4_t){0.f, 0.f, 0.f, 0.f};

    // prologue: stage kt=0 into buf 0
    GLOAD_LDS16(Kh  + khead + koff0, &Ks[0][c0 * 512]);
    GLOAD_LDS16(Kh  + khead + koff1, &Ks[0][c1 * 512]);
    GLOAD_LDS16(VtG + vg0,           &Vt[0][c0 * 512]);
    GLOAD_LDS16(VtG + vg1,           &Vt[0][c1 * 512]);

    for (int kt = 0; kt <= T0 + 1; kt++) {
        const int buf = kt & 1;
        __syncthreads();                     // staging of buf done; prev reads of buf^1 done
        if (kt <= T0) {                      // prefetch kt+1 into the other buffer
            const int nb = buf ^ 1;
            const size_t kg = khead + (size_t)(kt + 1) * 4096;
            GLOAD_LDS16(Kh  + kg + koff0,            &Ks[nb][c0 * 512]);
            GLOAD_LDS16(Kh  + kg + koff1,            &Ks[nb][c1 * 512]);
            GLOAD_LDS16(VtG + vg0 + (kt + 1) * 64,   &Vt[nb][c0 * 512]);
            GLOAD_LDS16(VtG + vg1 + (kt + 1) * 64,   &Vt[nb][c1 * 512]);
        }

        // K fragments (A for S^T), shared across both q-subtiles
        bf16x8_t kf[4][2], vf[4][2];
#pragma unroll
        for (int nt = 0; nt < 4; nt++) {
            kf[nt][0] = *reinterpret_cast<const bf16x8_t*>(&Ks[buf][ka[nt][0]]);
            kf[nt][1] = *reinterpret_cast<const bf16x8_t*>(&Ks[buf][ka[nt][1]]);
        }
#pragma unroll
        for (int dt = 0; dt < 4; dt++) {
            vf[dt][0] = *reinterpret_cast<const bf16x8_t*>(&Vt[buf][ka[dt][0]]);
            vf[dt][1] = *reinterpret_cast<const bf16x8_t*>(&Vt[buf][ka[dt][1]]);
        }

        const int mode0 = (kt < T0) ? 0 : ((kt == T0) ? 1 : 2);   // sub0
        const int mode1 = (kt <= T0) ? 0 : 1;                     // sub1

#pragma unroll
        for (int s = 0; s < 2; s++) {
            const int mode = s ? mode1 : mode0;
            if (mode == 2) continue;          // fully masked: contributes 0

            // ---- S^T = K * Q^T : C-layout row=k_l, col=q_l ----
            floatx4_t st[4];
#pragma unroll
            for (int nt = 0; nt < 4; nt++) {
                floatx4_t acc = (floatx4_t){0.f, 0.f, 0.f, 0.f};
                acc = __builtin_amdgcn_mfma_f32_16x16x32_bf16(kf[nt][0], qa[s][0], acc, 0, 0, 0);
                acc = __builtin_amdgcn_mfma_f32_16x16x32_bf16(kf[nt][1], qa[s][1], acc, 0, 0, 0);
                st[nt] = acc;
            }

            // ---- sigmoid -> P, packed b64 writes (4 consecutive k) ----
#pragma unroll
            for (int nt = 0; nt < 4; nt++) {
                bf16x4_t pk;
#pragma unroll
                for (int r = 0; r < 4; r++) {
                    float a = st[nt][r];
                    if (mode == 1) {
                        int kl = nt * 16 + quad * 4 + r;
                        a = (kl <= wl) ? a : __builtin_inff();  // exp2(inf)->rcp->0
                    }
                    float p = __builtin_amdgcn_rcpf(1.f + __builtin_amdgcn_exp2f(a));
                    pk[r] = (__bf16)p;
                }
                *reinterpret_cast<bf16x4_t*>(&Ps[wave][ln][nt * 16 + quad * 4]) = pk;
            }

            // ---- O += P V ----
            const __bf16* prow = &Ps[wave][ln][quad * 8];
            bf16x8_t p0 = *reinterpret_cast<const bf16x8_t*>(prow);
            bf16x8_t p1 = *reinterpret_cast<const bf16x8_t*>(prow + 32);
#pragma unroll
            for (int dt = 0; dt < 4; dt++) {
                o[s][dt] = __builtin_amdgcn_mfma_f32_16x16x32_bf16(p0, vf[dt][0], o[s][dt], 0, 0, 0);
                o[s][dt] = __builtin_amdgcn_mfma_f32_16x16x32_bf16(p1, vf[dt][1], o[s][dt], 0, 0, 0);
            }
        }
    }

    // write attn_out[b, q, h*64+d]  (C-layout: row=quad*4+reg, col=ln)
#pragma unroll
    for (int s = 0; s < 2; s++) {
        const int qrow_g = b * S_ + Q0 + s * 64 + wave * 16 + quad * 4;
#pragma unroll
        for (int dt = 0; dt < 4; dt++) {
#pragma unroll
            for (int reg = 0; reg < 4; reg++) {
                attn_out[(size_t)(qrow_g + reg) * H + h * 64 + dt * 16 + ln] =
                    (__bf16)o[s][dt][reg];
            }
        }
    }
}

// ---------------------------------------------------------------------------
// LayerNorm over H + SiLU(U from Ug) gating -> bf16 gated.
// ---------------------------------------------------------------------------
__global__ __launch_bounds__(256)
void ln_gate_kernel(const __bf16* __restrict__ attn_out, const __bf16* __restrict__ Ug,
                    const float* __restrict__ ln_g, const float* __restrict__ ln_b,
                    __bf16* __restrict__ gated)
{
    const int row = blockIdx.x;
    const int tid = threadIdx.x;

    bf16x4_t vb = *reinterpret_cast<const bf16x4_t*>(&attn_out[(size_t)row * H + tid * 4]);
    float v0 = (float)vb[0], v1 = (float)vb[1], v2 = (float)vb[2], v3 = (float)vb[3];
    float s  = v0 + v1 + v2 + v3;
    float sq = v0 * v0 + v1 * v1 + v2 * v2 + v3 * v3;
#pragma unroll
    for (int off = 32; off > 0; off >>= 1) {
        s  += __shfl_down(s, off);
        sq += __shfl_down(sq, off);
    }
    __shared__ float ps[4], pq[4];
    int wave = tid >> 6, lane = tid & 63;
    if (lane == 0) { ps[wave] = s; pq[wave] = sq; }
    __syncthreads();
    float ts = ps[0] + ps[1] + ps[2] + ps[3];
    float tq = pq[0] + pq[1] + pq[2] + pq[3];
    float mu  = ts * (1.f / (float)H);
    float var = tq * (1.f / (float)H) - mu * mu;
    float rstd = rsqrtf(var + 1e-8f);

    bf16x4_t ub = *reinterpret_cast<const bf16x4_t*>(&Ug[(size_t)row * 1024 + tid * 4]);
    float4 g  = *reinterpret_cast<const float4*>(&ln_g[tid * 4]);
    float4 bb = *reinterpret_cast<const float4*>(&ln_b[tid * 4]);
    float u0 = (float)ub[0], u1 = (float)ub[1], u2 = (float)ub[2], u3 = (float)ub[3];
    bf16x4_t outv;
    outv[0] = (__bf16)(((v0 - mu) * rstd * g.x + bb.x) * (u0 / (1.f + __expf(-u0))));
    outv[1] = (__bf16)(((v1 - mu) * rstd * g.y + bb.y) * (u1 / (1.f + __expf(-u1))));
    outv[2] = (__bf16)(((v2 - mu) * rstd * g.z + bb.z) * (u2 / (1.f + __expf(-u2))));
    outv[3] = (__bf16)(((v3 - mu) * rstd * g.w + bb.w) * (u3 / (1.f + __expf(-u3))));
    *reinterpret_cast<bf16x4_t*>(&gated[(size_t)row * H + tid * 4]) = outv;
}

// ---------------------------------------------------------------------------
extern "C" void kernel_launch(void* const* d_in, const int* in_sizes, int n_in,
                              void* d_out, int out_size, void* d_ws, size_t ws_size,
                              hipStream_t stream)
{
    const float* x    = (const float*)d_in[0];
    // d_in[1] = attn_mask: structurally causal tril; causality computed from indices.
    const float* Wp   = (const float*)d_in[2];
    const float* bp   = (const float*)d_in[3];
    const float* ln_g = (const float*)d_in[4];
    const float* ln_b = (const float*)d_in[5];
    const float* Wt   = (const float*)d_in[6];
    const float* bt   = (const float*)d_in[7];
    float* out = (float*)d_out;

    char* ws = (char*)d_ws;
    const size_t MB = 1024 * 1024;
    __bf16* Ug    = (__bf16*)(ws);              // 16 MB
    __bf16* Vh    = (__bf16*)(ws + 16  * MB);   // 16 MB
    __bf16* Qh    = (__bf16*)(ws + 32  * MB);   // 16 MB
    __bf16* Kh    = (__bf16*)(ws + 48  * MB);   // 16 MB
    __bf16* attn  = (__bf16*)(ws + 64  * MB);   // 16 MB
    __bf16* gated = (__bf16*)(ws + 80  * MB);   // 16 MB
    __bf16* VtG   = (__bf16*)(ws + 96  * MB);   // 16 MB
    __bf16* Ax    = (__bf16*)(ws + 112 * MB);   // 16 MB
    __bf16* Wp_t  = (__bf16*)(ws + 128 * MB);   //  8 MB
    __bf16* Wt_t  = (__bf16*)(ws + 136 * MB);   //  2 MB

    prep_kernel<<<13312, 256, 0, stream>>>(x, Wp, Wt, Ax, Wp_t, Wt_t);

    dim3 g1(4096 / 256, ROWS / 256);
    gemm_proj<<<g1, 512, 0, stream>>>(Ax, Wp_t, bp, Ug, Vh, Qh, Kh);

    transpose_v<<<dim3(S_ / 64, B_ * NH), 256, 0, stream>>>(Vh, VtG);

    attn_mfma<<<(S_ / 128) * NH * B_, 256, 0, stream>>>(Qh, Kh, VtG, attn);

    ln_gate_kernel<<<ROWS, 256, 0, stream>>>(attn, Ug, ln_g, ln_b, gated);

    dim3 g3(1024 / 128, ROWS / 128);
    gemm_out<<<g3, 256, 0, stream>>>(gated, Wt_t, bt, x, out, ROWS, 1024, 1024);
}

// Round 2
// 325.129 us; speedup vs baseline: 1.0587x; 1.0488x over previous
//
#include <hip/hip_runtime.h>
#include <math.h>

#define H 1024
#define NH 16
#define HD 64
#define B_ 4
#define S_ 2048
#define ROWS (B_*S_)   // 8192

// -0.125 * log2(e): folded into Qh so sigmoid(s*0.125) = rcp(1 + exp2(dot))
#define QSCALE (-0.1803368801111664f)
#define ROPE_C (9.210340371976184f / 32.0f)   // ln(10000)/32

typedef __bf16 bf16x2_t __attribute__((ext_vector_type(2)));
typedef __bf16 bf16x4_t __attribute__((ext_vector_type(4)));
typedef __bf16 bf16x8_t __attribute__((ext_vector_type(8)));
typedef float floatx4_t __attribute__((ext_vector_type(4)));
typedef float floatx16_t __attribute__((ext_vector_type(16)));

// async global->LDS, 16B per lane, dest = wave-uniform base + lane*16
#define GLOAD_LDS16(gp, lp)                                                        \
    __builtin_amdgcn_global_load_lds(                                              \
        (const __attribute__((address_space(1))) unsigned int*)(gp),               \
        (__attribute__((address_space(3))) unsigned int*)(lp), 16, 0, 0)

// ---------------------------------------------------------------------------
// Fused prep: x->bf16 copy, Wp transpose+cvt, Wt transpose+cvt (one dispatch)
// ---------------------------------------------------------------------------
__global__ __launch_bounds__(256)
void prep_kernel(const float* __restrict__ x, const float* __restrict__ Wp,
                 const float* __restrict__ Wt,
                 __bf16* __restrict__ Ax, __bf16* __restrict__ Wp_t,
                 __bf16* __restrict__ Wt_t)
{
    __shared__ __bf16 t[32][33];
    const int flat = blockIdx.x;
    const int tid = threadIdx.x;

    if (flat < 8192) {
        size_t i = (size_t)flat * 256 + tid;
        float4 v = *reinterpret_cast<const float4*>(&x[i * 4]);
        bf16x4_t w = { (__bf16)v.x, (__bf16)v.y, (__bf16)v.z, (__bf16)v.w };
        *reinterpret_cast<bf16x4_t*>(&Ax[i * 4]) = w;
        return;
    }
    const float* W; __bf16* Wo; int K, N, bn, bk;
    if (flat < 12288) {
        int id = flat - 8192;  W = Wp; Wo = Wp_t; K = 1024; N = 4096;
        bn = (id & 127) * 32;  bk = (id >> 7) * 32;
    } else {
        int id = flat - 12288; W = Wt; Wo = Wt_t; K = 1024; N = 1024;
        bn = (id & 31) * 32;   bk = (id >> 5) * 32;
    }
    const int tx = tid & 31, ty = tid >> 5;
#pragma unroll
    for (int i = 0; i < 4; i++) {
        int r = ty + i * 8;
        t[tx][r] = (__bf16)W[(size_t)(bk + r) * N + bn + tx];
    }
    __syncthreads();
#pragma unroll
    for (int i = 0; i < 4; i++) {
        int r = ty + i * 8;
        Wo[(size_t)(bn + r) * K + bk + tx] = t[r][tx];
    }
}

// ===========================================================================
// gemm_proj: 256x256 tile, BK=64, 8 waves (2M x 4N), 8-phase HK schedule
// (T2 swizzle + T3/T4 counted-vmcnt + T5 setprio), 16x16x32 MFMA.
// (unchanged from R0 — 96.8 -> 75.3 us, conflicts 8.4M -> 0)
// ===========================================================================

#define MIN15(x) ((x) < 15 ? (x) : 15)

#define STAGE_A(buf, h, tile) do { int _kb = (tile) * 64 + (h) * 32;               \
        char* _lb = lwA + ((buf) * 2 + (h)) * 16384;                               \
        GLOAD_LDS16(a_src0 + _kb, _lb);                                            \
        GLOAD_LDS16(a_src1 + _kb, _lb + 1024); } while (0)
#define STAGE_B(buf, h, tile) do { int _kb = (tile) * 64 + (h) * 32;               \
        char* _lb = lwB + ((buf) * 2 + (h)) * 16384;                               \
        GLOAD_LDS16(b_src0 + _kb, _lb);                                            \
        GLOAD_LDS16(b_src1 + _kb, _lb + 1024); } while (0)

__global__ __launch_bounds__(512, 2)
void gemm_proj(const __bf16* __restrict__ A, const __bf16* __restrict__ Bt,
               const float* __restrict__ bias,
               __bf16* __restrict__ Ug, __bf16* __restrict__ Vh,
               __bf16* __restrict__ Qh, __bf16* __restrict__ Kh)
{
    __shared__ __attribute__((aligned(16))) char smem[131072];

    const int tid  = threadIdx.x;
    const int wave = tid >> 6, lane = tid & 63;
    const int ln15 = lane & 15, q4 = lane >> 4;
    const int wm = wave & 1, wn = wave >> 1;
    const int m0 = blockIdx.y * 256, n0 = blockIdx.x * 256;

    // ---- staging constants: linear LDS dest, inverse-swizzled global src ----
    const int srow0 = wave * 32 + (lane >> 2);            // row for load p=0
    const int csrc  = (lane & 3) ^ ((lane >> 3) & 3);     // swizzled 16B chunk
    const __bf16* a_src0 = A  + (size_t)(m0 + srow0) * 1024 + csrc * 8;
    const __bf16* a_src1 = a_src0 + (size_t)16 * 1024;    // row +16 (load p=1)
    const __bf16* b_src0 = Bt + (size_t)(n0 + srow0) * 1024 + csrc * 8;
    const __bf16* b_src1 = b_src0 + (size_t)16 * 1024;
    char* lwA = smem + wave * 2048;                       // + slot*16384
    char* lwB = smem + 65536 + wave * 2048;

    // ---- fragment read offsets (swizzled) ----
    const int sl = (ln15 >> 1) & 3;
    const int a_lane = (wm * 128 + ln15) * 64 + ((q4 ^ sl) << 4);
    const int b_lane = (wn * 64  + ln15) * 64 + ((q4 ^ sl) << 4);

    floatx4_t acc[8][4];
#pragma unroll
    for (int i = 0; i < 8; i++)
#pragma unroll
        for (int j = 0; j < 4; j++) acc[i][j] = (floatx4_t){0.f, 0.f, 0.f, 0.f};

    // ---- prologue: T0 all 4 halves + T1 {Bk0, Ak0, Bk1}, FIFO order ----
    STAGE_B(0, 0, 0); STAGE_A(0, 0, 0); STAGE_B(0, 1, 0); STAGE_A(0, 1, 0);
    STAGE_B(1, 0, 1); STAGE_A(1, 0, 1); STAGE_B(1, 1, 1);
    asm volatile("s_waitcnt vmcnt(6)" ::: "memory");   // T0 landed
    __builtin_amdgcn_s_barrier();

    bf16x8_t bfr[4];

    for (int it = 0; it < 8; ++it) {
        const int T = 2 * it;
#pragma unroll
        for (int p = 0; p < 8; ++p) {
            const int buf = p >> 2, sub = p & 3, mh = sub & 1, kk = sub >> 1;
            const char* asl = smem + (buf * 2 + kk) * 16384;
            const char* bsl = smem + 65536 + (buf * 2 + kk) * 16384;

            // ds-loads for this phase
            if ((sub & 1) == 0) {
#pragma unroll
                for (int nf = 0; nf < 4; nf++)
                    bfr[nf] = *reinterpret_cast<const bf16x8_t*>(bsl + b_lane + nf * 1024);
            }
            bf16x8_t af[4];
#pragma unroll
            for (int mfi = 0; mfi < 4; mfi++)
                af[mfi] = *reinterpret_cast<const bf16x8_t*>(asl + a_lane + (mh * 4 + mfi) * 1024);

            // stage one half-tile
            if      (p == 0) STAGE_A(1, 1, MIN15(T + 1));
            else if (p == 1) STAGE_B(0, 0, MIN15(T + 2));
            else if (p == 2) STAGE_A(0, 0, MIN15(T + 2));
            else if (p == 3) STAGE_B(0, 1, MIN15(T + 2));
            else if (p == 4) STAGE_A(0, 1, MIN15(T + 2));
            else if (p == 5) STAGE_B(1, 0, MIN15(T + 3));
            else if (p == 6) STAGE_A(1, 0, MIN15(T + 3));
            else             STAGE_B(1, 1, MIN15(T + 3));

            if (p == 3 || p == 7)
                asm volatile("s_waitcnt vmcnt(6)" ::: "memory");
            __builtin_amdgcn_s_barrier();

            __builtin_amdgcn_s_setprio(1);
#pragma unroll
            for (int nf = 0; nf < 4; nf++)
#pragma unroll
                for (int mfi = 0; mfi < 4; mfi++)
                    acc[mh * 4 + mfi][nf] = __builtin_amdgcn_mfma_f32_16x16x32_bf16(
                        af[mfi], bfr[nf], acc[mh * 4 + mfi][nf], 0, 0, 0);
            __builtin_amdgcn_s_setprio(0);
            __builtin_amdgcn_s_barrier();
        }
    }
    asm volatile("s_waitcnt vmcnt(0)" ::: "memory");

    // ---- split epilogue (block-uniform region branch) ----
    const int colbase = n0 + wn * 64;
    float bv[4];
#pragma unroll
    for (int nf = 0; nf < 4; nf++) bv[nf] = bias[colbase + nf * 16 + ln15];

    const int rowb = m0 + wm * 128 + q4 * 4;   // + mf*16 + reg

    if (n0 < 1024) {
#pragma unroll
        for (int mf = 0; mf < 8; mf++)
#pragma unroll
            for (int nf = 0; nf < 4; nf++) {
                int col = colbase + nf * 16 + ln15;
#pragma unroll
                for (int reg = 0; reg < 4; reg++) {
                    int row = rowb + mf * 16 + reg;
                    Ug[(size_t)row * 1024 + col] = (__bf16)(acc[mf][nf][reg] + bv[nf]);
                }
            }
    } else if (n0 < 2048) {
        const int h = ((n0 - 1024) >> 6) + wn;    // wave spans one head
#pragma unroll
        for (int mf = 0; mf < 8; mf++)
#pragma unroll
            for (int reg = 0; reg < 4; reg++) {
                int row = rowb + mf * 16 + reg;
                int b = row >> 11, s = row & (S_ - 1);
                size_t orow = ((size_t)(b * NH + h) * S_ + s) * 64;
#pragma unroll
                for (int nf = 0; nf < 4; nf++)
                    Vh[orow + nf * 16 + ln15] = (__bf16)(acc[mf][nf][reg] + bv[nf]);
            }
    } else {
        const bool isQ = (n0 < 3072);
        const int h = ((n0 - (isQ ? 2048 : 3072)) >> 6) + wn;
        __bf16* dst = isQ ? Qh : Kh;
        const float sc = isQ ? QSCALE : 1.0f;
        float inv[2];
        inv[0] = __expf(-(float)(ln15)      * ROPE_C);
        inv[1] = __expf(-(float)(16 + ln15) * ROPE_C);
#pragma unroll
        for (int mf = 0; mf < 8; mf++)
#pragma unroll
            for (int reg = 0; reg < 4; reg++) {
                int row = rowb + mf * 16 + reg;
                int b = row >> 11, s = row & (S_ - 1);
                size_t orow = ((size_t)(b * NH + h) * S_ + s) * 64;
#pragma unroll
                for (int nf = 0; nf < 2; nf++) {
                    float sn, cs;
                    __sincosf((float)s * inv[nf], &sn, &cs);
                    float lo = acc[mf][nf][reg]     + bv[nf];
                    float hi = acc[mf][nf + 2][reg] + bv[nf + 2];
                    int d = nf * 16 + ln15;
                    dst[orow + d]      = (__bf16)((lo * cs - hi * sn) * sc);
                    dst[orow + 32 + d] = (__bf16)((hi * cs + lo * sn) * sc);
                }
            }
    }
}

// ---------------------------------------------------------------------------
// out-proj GEMM: C = A @ Bt^T + bias + resid (fp32 out). 128x128, m97 struct.
// ---------------------------------------------------------------------------
__global__ __launch_bounds__(256)
void gemm_out(const __bf16* __restrict__ A, const __bf16* __restrict__ Bt,
              const float* __restrict__ bias, const float* __restrict__ resid,
              float* __restrict__ C, int M, int N, int K)
{
    __shared__ __bf16 As[128 * 32];
    __shared__ __bf16 Bs[128 * 32];

    const int tid  = threadIdx.x;
    const int wave = tid >> 6, lane = tid & 63;
    const int l31 = lane & 31, half = lane >> 5;
    const int wm = wave & 1, wn = wave >> 1;
    const int m0 = blockIdx.y * 128, n0 = blockIdx.x * 128;

    const int srow = lane >> 2;
    const int skc  = (((lane & 3) ^ ((srow >> 1) & 3)) * 8);

    const int fsw = (l31 >> 1) & 3;
    int aoff[2][2], boff[2][2];
#pragma unroll
    for (int mt = 0; mt < 2; mt++)
#pragma unroll
        for (int ks = 0; ks < 2; ks++) {
            int ra = wm * 64 + mt * 32 + l31;
            int rb = wn * 64 + mt * 32 + l31;
            int c = ks * 2 + half;
            aoff[mt][ks] = ra * 32 + ((c ^ fsw) * 8);
            boff[mt][ks] = rb * 32 + ((c ^ fsw) * 8);
        }

    floatx16_t acc[2][2];
#pragma unroll
    for (int i = 0; i < 2; i++)
#pragma unroll
        for (int j = 0; j < 2; j++) acc[i][j] = (floatx16_t)(0.f);

    for (int k0 = 0; k0 < K; k0 += 32) {
#pragma unroll
        for (int p = 0; p < 2; p++) {
            int i = wave * 2 + p;
            int rl = i * 16 + srow;
            GLOAD_LDS16(A  + (size_t)(m0 + rl) * K + k0 + skc, &As[i * 512]);
            GLOAD_LDS16(Bt + (size_t)(n0 + rl) * K + k0 + skc, &Bs[i * 512]);
        }
        __syncthreads();

        bf16x8_t af[2][2], bf[2][2];
#pragma unroll
        for (int mt = 0; mt < 2; mt++)
#pragma unroll
            for (int ks = 0; ks < 2; ks++) {
                af[mt][ks] = *reinterpret_cast<const bf16x8_t*>(&As[aoff[mt][ks]]);
                bf[mt][ks] = *reinterpret_cast<const bf16x8_t*>(&Bs[boff[mt][ks]]);
            }
#pragma unroll
        for (int ks = 0; ks < 2; ks++)
#pragma unroll
            for (int mt = 0; mt < 2; mt++)
#pragma unroll
                for (int nt = 0; nt < 2; nt++)
                    acc[mt][nt] = __builtin_amdgcn_mfma_f32_32x32x16_bf16(
                        af[mt][ks], bf[nt][ks], acc[mt][nt], 0, 0, 0);
        __syncthreads();
    }

#pragma unroll
    for (int mt = 0; mt < 2; mt++) {
#pragma unroll
        for (int nt = 0; nt < 2; nt++) {
            int col = n0 + wn * 64 + nt * 32 + l31;
            float bv = bias[col];
#pragma unroll
            for (int reg = 0; reg < 16; reg++) {
                int rowf = (reg & 3) + 8 * (reg >> 2) + 4 * half;
                int row = m0 + wm * 64 + mt * 32 + rowf;
                C[(size_t)row * N + col] = acc[mt][nt][reg] + bv + resid[(size_t)row * N + col];
            }
        }
    }
}

// ---------------------------------------------------------------------------
// V transpose: Vh[bh][s][64] -> VtG[bh][d][S]
// ---------------------------------------------------------------------------
__global__ __launch_bounds__(256)
void transpose_v(const __bf16* __restrict__ Vh, __bf16* __restrict__ VtG)
{
    const int tid = threadIdx.x;
    const int st = blockIdx.x, bh = blockIdx.y;
    const int s0 = st * 64;
    const int d = tid & 63, k16 = tid >> 6;
    __bf16 vals[16];
#pragma unroll
    for (int j = 0; j < 16; j++) {
        int k = s0 + k16 * 16 + j;
        vals[j] = Vh[((size_t)bh * S_ + k) * 64 + d];
    }
    size_t orow = ((size_t)(bh * 64 + d)) * S_ + s0 + k16 * 16;
    *reinterpret_cast<bf16x8_t*>(&VtG[orow])     = *reinterpret_cast<bf16x8_t*>(&vals[0]);
    *reinterpret_cast<bf16x8_t*>(&VtG[orow + 8]) = *reinterpret_cast<bf16x8_t*>(&vals[8]);
}

// ---------------------------------------------------------------------------
// Sigmoid attention, causal, bf16 MFMA.
// R1 restructure: 8 waves (512 thr), ONE 16-row q-subtile per wave (halves
// each wave's serial QK->sigmoid->PV chain, doubles wave-level overlap), and
// qt-PAIRING for perfect load balance: block p does qt=15-p then qt=p, so
// every block runs exactly 36 k-tile iters. Grid 512 uniform blocks -> all
// resident (LDS 50KB -> 3 blocks/CU cap, need 2). Inter-half safety: half A's
// last iter reads only buf1 (T0 even), so half B's prologue restage of buf0
// is behind the kt=T0+1 barrier; half B's first buf1 write is behind its
// kt=0 barrier. Barrier count is uniform across waves.
// ---------------------------------------------------------------------------
__global__ __launch_bounds__(512, 4)
void attn_mfma(const __bf16* __restrict__ Qh, const __bf16* __restrict__ Kh,
               const __bf16* __restrict__ VtG, __bf16* __restrict__ attn_out)
{
    __shared__ __bf16 Ks[2][4096];     // 64x64 K[k][d], swizzled
    __shared__ __bf16 Vt[2][4096];     // 64x64 V^T[d][k], swizzled
    __shared__ __bf16 Ps[8][16][72];   // per-wave P strip

    const int tid = threadIdx.x, wave = tid >> 6, lane = tid & 63;
    const int quad = lane >> 4, ln = lane & 15;
    const int p  = blockIdx.x >> 6;                       // pair id 0..7
    const int hb = blockIdx.x & 63, h = hb & 15, b = hb >> 4, bh = b * NH + h;

    // staging lane constants (XOR swizzle: LDS[row][c] = global[row][c^(row&7)])
    const int sr = lane >> 3, scl = (lane & 7) ^ sr;
    const size_t khead = (size_t)bh * S_ * 64;
    const int koff = (wave * 8 + sr) * 64 + scl * 8;      // chunk = wave
    const size_t vg = ((size_t)bh * 64 + wave * 8 + sr) * S_ + scl * 8;

    // fragment LDS element offsets (kt-invariant, swizzled)
    const int m7 = ln & 7;
    int ka[4][2];
#pragma unroll
    for (int nt = 0; nt < 4; nt++) {
        int row = nt * 16 + ln;
        ka[nt][0] = row * 64 + ((quad ^ m7) << 3);
        ka[nt][1] = row * 64 + (((quad + 4) ^ m7) << 3);
    }

    const int wl   = wave * 16 + ln;   // q-row local in [0,128)
    const int wl63 = wl & 63;          // diag-mask comparand (both wave groups)
    const bool hiw = wave >= 4;

    for (int hf = 0; hf < 2; hf++) {
        const int qt = hf ? p : (15 - p);
        const int Q0 = qt * 128, T0 = 2 * qt;

        // Q fragments: loop-invariant, direct from global (one subtile, K=64)
        const size_t qr = ((size_t)bh * S_ + Q0 + wl) * 64;
        const bf16x8_t qa0 = *reinterpret_cast<const bf16x8_t*>(&Qh[qr + quad * 8]);
        const bf16x8_t qa1 = *reinterpret_cast<const bf16x8_t*>(&Qh[qr + 32 + quad * 8]);

        floatx4_t o[4];
#pragma unroll
        for (int dt = 0; dt < 4; dt++) o[dt] = (floatx4_t){0.f, 0.f, 0.f, 0.f};

        // prologue: stage kt=0 into buf 0 (safe across halves — see header)
        GLOAD_LDS16(Kh  + khead + koff, &Ks[0][wave * 512]);
        GLOAD_LDS16(VtG + vg,           &Vt[0][wave * 512]);

        for (int kt = 0; kt <= T0 + 1; kt++) {
            const int buf = kt & 1;
            __syncthreads();                 // staging of buf done; prior reads of buf^1 done
            if (kt <= T0) {                  // prefetch kt+1 into the other buffer
                const int nb = buf ^ 1;
                GLOAD_LDS16(Kh  + khead + (size_t)(kt + 1) * 4096 + koff, &Ks[nb][wave * 512]);
                GLOAD_LDS16(VtG + vg + (kt + 1) * 64,                      &Vt[nb][wave * 512]);
            }

            // mode: 0 full, 1 diag, 2 skip (fully masked)
            const int rel = kt - T0;
            const int mode = (rel < 0) ? 0 : (rel == 0 ? (hiw ? 0 : 1) : (hiw ? 1 : 2));
            if (mode == 2) continue;

            // K fragments (A for S^T)
            bf16x8_t kf[4][2];
#pragma unroll
            for (int nt = 0; nt < 4; nt++) {
                kf[nt][0] = *reinterpret_cast<const bf16x8_t*>(&Ks[buf][ka[nt][0]]);
                kf[nt][1] = *reinterpret_cast<const bf16x8_t*>(&Ks[buf][ka[nt][1]]);
            }

            // ---- S^T = K * Q^T : C-layout row=k_l, col=q_l ----
            floatx4_t st[4];
#pragma unroll
            for (int nt = 0; nt < 4; nt++) {
                floatx4_t acc = (floatx4_t){0.f, 0.f, 0.f, 0.f};
                acc = __builtin_amdgcn_mfma_f32_16x16x32_bf16(kf[nt][0], qa0, acc, 0, 0, 0);
                acc = __builtin_amdgcn_mfma_f32_16x16x32_bf16(kf[nt][1], qa1, acc, 0, 0, 0);
                st[nt] = acc;
            }

            // ---- sigmoid -> P, packed b64 writes (4 consecutive k) ----
#pragma unroll
            for (int nt = 0; nt < 4; nt++) {
                bf16x4_t pk;
#pragma unroll
                for (int r = 0; r < 4; r++) {
                    float a = st[nt][r];
                    if (mode == 1) {
                        int kl = nt * 16 + quad * 4 + r;
                        a = (kl <= wl63) ? a : __builtin_inff();  // exp2(inf)->rcp->0
                    }
                    float pv = __builtin_amdgcn_rcpf(1.f + __builtin_amdgcn_exp2f(a));
                    pk[r] = (__bf16)pv;
                }
                *reinterpret_cast<bf16x4_t*>(&Ps[wave][ln][nt * 16 + quad * 4]) = pk;
            }

            // V fragments (read late to shorten live range)
            bf16x8_t vf[4][2];
#pragma unroll
            for (int dt = 0; dt < 4; dt++) {
                vf[dt][0] = *reinterpret_cast<const bf16x8_t*>(&Vt[buf][ka[dt][0]]);
                vf[dt][1] = *reinterpret_cast<const bf16x8_t*>(&Vt[buf][ka[dt][1]]);
            }

            // ---- O += P V ----
            const __bf16* prow = &Ps[wave][ln][quad * 8];
            bf16x8_t p0 = *reinterpret_cast<const bf16x8_t*>(prow);
            bf16x8_t p1 = *reinterpret_cast<const bf16x8_t*>(prow + 32);
#pragma unroll
            for (int dt = 0; dt < 4; dt++) {
                o[dt] = __builtin_amdgcn_mfma_f32_16x16x32_bf16(p0, vf[dt][0], o[dt], 0, 0, 0);
                o[dt] = __builtin_amdgcn_mfma_f32_16x16x32_bf16(p1, vf[dt][1], o[dt], 0, 0, 0);
            }
        }

        // write attn_out[b, q, h*64+d]  (C-layout: row=quad*4+reg, col=ln)
        const int qrow_g = b * S_ + Q0 + wave * 16 + quad * 4;
#pragma unroll
        for (int dt = 0; dt < 4; dt++) {
#pragma unroll
            for (int reg = 0; reg < 4; reg++) {
                attn_out[(size_t)(qrow_g + reg) * H + h * 64 + dt * 16 + ln] =
                    (__bf16)o[dt][reg];
            }
        }
    }
}

// ---------------------------------------------------------------------------
// LayerNorm over H + SiLU(U from Ug) gating -> bf16 gated.
// ---------------------------------------------------------------------------
__global__ __launch_bounds__(256)
void ln_gate_kernel(const __bf16* __restrict__ attn_out, const __bf16* __restrict__ Ug,
                    const float* __restrict__ ln_g, const float* __restrict__ ln_b,
                    __bf16* __restrict__ gated)
{
    const int row = blockIdx.x;
    const int tid = threadIdx.x;

    bf16x4_t vb = *reinterpret_cast<const bf16x4_t*>(&attn_out[(size_t)row * H + tid * 4]);
    float v0 = (float)vb[0], v1 = (float)vb[1], v2 = (float)vb[2], v3 = (float)vb[3];
    float s  = v0 + v1 + v2 + v3;
    float sq = v0 * v0 + v1 * v1 + v2 * v2 + v3 * v3;
#pragma unroll
    for (int off = 32; off > 0; off >>= 1) {
        s  += __shfl_down(s, off);
        sq += __shfl_down(sq, off);
    }
    __shared__ float ps[4], pq[4];
    int wave = tid >> 6, lane = tid & 63;
    if (lane == 0) { ps[wave] = s; pq[wave] = sq; }
    __syncthreads();
    float ts = ps[0] + ps[1] + ps[2] + ps[3];
    float tq = pq[0] + pq[1] + pq[2] + pq[3];
    float mu  = ts * (1.f / (float)H);
    float var = tq * (1.f / (float)H) - mu * mu;
    float rstd = rsqrtf(var + 1e-8f);

    bf16x4_t ub = *reinterpret_cast<const bf16x4_t*>(&Ug[(size_t)row * 1024 + tid * 4]);
    float4 g  = *reinterpret_cast<const float4*>(&ln_g[tid * 4]);
    float4 bb = *reinterpret_cast<const float4*>(&ln_b[tid * 4]);
    float u0 = (float)ub[0], u1 = (float)ub[1], u2 = (float)ub[2], u3 = (float)ub[3];
    bf16x4_t outv;
    outv[0] = (__bf16)(((v0 - mu) * rstd * g.x + bb.x) * (u0 / (1.f + __expf(-u0))));
    outv[1] = (__bf16)(((v1 - mu) * rstd * g.y + bb.y) * (u1 / (1.f + __expf(-u1))));
    outv[2] = (__bf16)(((v2 - mu) * rstd * g.z + bb.z) * (u2 / (1.f + __expf(-u2))));
    outv[3] = (__bf16)(((v3 - mu) * rstd * g.w + bb.w) * (u3 / (1.f + __expf(-u3))));
    *reinterpret_cast<bf16x4_t*>(&gated[(size_t)row * H + tid * 4]) = outv;
}

// ---------------------------------------------------------------------------
extern "C" void kernel_launch(void* const* d_in, const int* in_sizes, int n_in,
                              void* d_out, int out_size, void* d_ws, size_t ws_size,
                              hipStream_t stream)
{
    const float* x    = (const float*)d_in[0];
    // d_in[1] = attn_mask: structurally causal tril; causality computed from indices.
    const float* Wp   = (const float*)d_in[2];
    const float* bp   = (const float*)d_in[3];
    const float* ln_g = (const float*)d_in[4];
    const float* ln_b = (const float*)d_in[5];
    const float* Wt   = (const float*)d_in[6];
    const float* bt   = (const float*)d_in[7];
    float* out = (float*)d_out;

    char* ws = (char*)d_ws;
    const size_t MB = 1024 * 1024;
    __bf16* Ug    = (__bf16*)(ws);              // 16 MB
    __bf16* Vh    = (__bf16*)(ws + 16  * MB);   // 16 MB
    __bf16* Qh    = (__bf16*)(ws + 32  * MB);   // 16 MB
    __bf16* Kh    = (__bf16*)(ws + 48  * MB);   // 16 MB
    __bf16* attn  = (__bf16*)(ws + 64  * MB);   // 16 MB
    __bf16* gated = (__bf16*)(ws + 80  * MB);   // 16 MB
    __bf16* VtG   = (__bf16*)(ws + 96  * MB);   // 16 MB
    __bf16* Ax    = (__bf16*)(ws + 112 * MB);   // 16 MB
    __bf16* Wp_t  = (__bf16*)(ws + 128 * MB);   //  8 MB
    __bf16* Wt_t  = (__bf16*)(ws + 136 * MB);   //  2 MB

    prep_kernel<<<13312, 256, 0, stream>>>(x, Wp, Wt, Ax, Wp_t, Wt_t);

    dim3 g1(4096 / 256, ROWS / 256);
    gemm_proj<<<g1, 512, 0, stream>>>(Ax, Wp_t, bp, Ug, Vh, Qh, Kh);

    transpose_v<<<dim3(S_ / 64, B_ * NH), 256, 0, stream>>>(Vh, VtG);

    attn_mfma<<<8 * B_ * NH, 512, 0, stream>>>(Qh, Kh, VtG, attn);

    ln_gate_kernel<<<ROWS, 256, 0, stream>>>(attn, Ug, ln_g, ln_b, gated);

    dim3 g3(1024 / 128, ROWS / 128);
    gemm_out<<<g3, 256, 0, stream>>>(gated, Wt_t, bt, x, out, ROWS, 1024, 1024);
}

// Round 3
// 319.458 us; speedup vs baseline: 1.0775x; 1.0178x over previous
//
#include <hip/hip_runtime.h>
#include <math.h>

#define H 1024
#define NH 16
#define HD 64
#define B_ 4
#define S_ 2048
#define ROWS (B_*S_)   // 8192

// -0.125 * log2(e): folded into Qh so sigmoid(s*0.125) = rcp(1 + exp2(dot))
#define QSCALE (-0.1803368801111664f)
#define ROPE_C (9.210340371976184f / 32.0f)   // ln(10000)/32

typedef __bf16 bf16x2_t __attribute__((ext_vector_type(2)));
typedef __bf16 bf16x4_t __attribute__((ext_vector_type(4)));
typedef __bf16 bf16x8_t __attribute__((ext_vector_type(8)));
typedef float floatx4_t __attribute__((ext_vector_type(4)));
typedef float floatx16_t __attribute__((ext_vector_type(16)));

// async global->LDS, 16B per lane, dest = wave-uniform base + lane*16
#define GLOAD_LDS16(gp, lp)                                                        \
    __builtin_amdgcn_global_load_lds(                                              \
        (const __attribute__((address_space(1))) unsigned int*)(gp),               \
        (__attribute__((address_space(3))) unsigned int*)(lp), 16, 0, 0)

// ---------------------------------------------------------------------------
// Fused prep: x->bf16 copy, Wp transpose+cvt, Wt transpose+cvt (one dispatch)
// ---------------------------------------------------------------------------
__global__ __launch_bounds__(256)
void prep_kernel(const float* __restrict__ x, const float* __restrict__ Wp,
                 const float* __restrict__ Wt,
                 __bf16* __restrict__ Ax, __bf16* __restrict__ Wp_t,
                 __bf16* __restrict__ Wt_t)
{
    __shared__ __bf16 t[32][33];
    const int flat = blockIdx.x;
    const int tid = threadIdx.x;

    if (flat < 8192) {
        size_t i = (size_t)flat * 256 + tid;
        float4 v = *reinterpret_cast<const float4*>(&x[i * 4]);
        bf16x4_t w = { (__bf16)v.x, (__bf16)v.y, (__bf16)v.z, (__bf16)v.w };
        *reinterpret_cast<bf16x4_t*>(&Ax[i * 4]) = w;
        return;
    }
    const float* W; __bf16* Wo; int K, N, bn, bk;
    if (flat < 12288) {
        int id = flat - 8192;  W = Wp; Wo = Wp_t; K = 1024; N = 4096;
        bn = (id & 127) * 32;  bk = (id >> 7) * 32;
    } else {
        int id = flat - 12288; W = Wt; Wo = Wt_t; K = 1024; N = 1024;
        bn = (id & 31) * 32;   bk = (id >> 5) * 32;
    }
    const int tx = tid & 31, ty = tid >> 5;
#pragma unroll
    for (int i = 0; i < 4; i++) {
        int r = ty + i * 8;
        t[tx][r] = (__bf16)W[(size_t)(bk + r) * N + bn + tx];
    }
    __syncthreads();
#pragma unroll
    for (int i = 0; i < 4; i++) {
        int r = ty + i * 8;
        Wo[(size_t)(bn + r) * K + bk + tx] = t[r][tx];
    }
}

// ===========================================================================
// gemm_proj R2: 128x256 tile, BK=32, 8 waves (2M x 4N), wave tile 64x64,
// 16x16x32 MFMA. Small footprint (48KB LDS, 64 acc VGPR) -> 2 blocks/CU
// (16 waves): barrier/vmcnt stalls of one block are filled by the other.
// Per K-step: 8 swizzled ds_read_b128 + 3 global_load_lds (prefetch T+1
// into idle buffer) + 16-MFMA setprio cluster + own-vmcnt(0) + 1 barrier.
// Swizzle (4-chunk rows): LDS[row][cw] holds global chunk cw^((row>>1)&3);
// staged via inverse-permuted global source (linear LDS dest, m104/m173);
// frag read chunk = q4 ^ ((row>>1)&3) -> 2 lanes/bank (free, m136).
// Ring audit: stage->nb issues after the barrier retiring nb's last reads;
// reads of T+1 are behind T's own-vmcnt(0)-then-barrier (per-wave drain
// before barrier => all waves' stages landed).
// C/D layout 16x16 (m89/m91): col=lane&15, row=(lane>>4)*4+reg.
// ===========================================================================

#define PSTAGE_A(tile, nb) GLOAD_LDS16(a_src + (size_t)(tile) * 32, &As[nb][wave * 512])
#define PSTAGE_B(tile, nb) do {                                                     \
        GLOAD_LDS16(b_src0 + (size_t)(tile) * 32, &Bs[nb][wave * 512]);             \
        GLOAD_LDS16(b_src1 + (size_t)(tile) * 32, &Bs[nb][4096 + wave * 512]); } while (0)

__global__ __launch_bounds__(512, 4)
void gemm_proj(const __bf16* __restrict__ A, const __bf16* __restrict__ Bt,
               const float* __restrict__ bias,
               __bf16* __restrict__ Ug, __bf16* __restrict__ Vh,
               __bf16* __restrict__ Qh, __bf16* __restrict__ Kh)
{
    __shared__ __attribute__((aligned(16))) __bf16 As[2][128 * 32];   // 16 KB
    __shared__ __attribute__((aligned(16))) __bf16 Bs[2][256 * 32];   // 32 KB

    const int tid  = threadIdx.x;
    const int wave = tid >> 6, lane = tid & 63;
    const int ln15 = lane & 15, q4 = lane >> 4;
    const int wm = wave & 1, wn = wave >> 1;

    // XCD-contiguous bijective swizzle (1024 % 8 == 0), n-major chunks:
    // consecutive work-ids on one XCD share the B panel (512KB, L2-friendly).
    const int bid = blockIdx.x;
    const int wid = (bid & 7) * 128 + (bid >> 3);
    const int m0 = (wid & 63) * 128;
    const int n0 = (wid >> 6) * 256;

    // ---- staging constants: linear LDS dest, inverse-swizzled global src ----
    const int srow = tid >> 2;                        // 0..127
    const int csrc = (tid & 3) ^ ((tid >> 3) & 3);    // source 16B chunk
    const __bf16* a_src  = A  + (size_t)(m0 + srow) * 1024 + csrc * 8;
    const __bf16* b_src0 = Bt + (size_t)(n0 + srow) * 1024 + csrc * 8;
    const __bf16* b_src1 = b_src0 + (size_t)128 * 1024;   // rows 128..255

    // ---- fragment read offsets (elements; kt-invariant, swizzled) ----
    int aoff[4], boff[4];
#pragma unroll
    for (int f = 0; f < 4; f++) {
        int ra = wm * 64 + f * 16 + ln15;
        aoff[f] = ra * 32 + ((q4 ^ ((ra >> 1) & 3)) * 8);
        int rb = wn * 64 + f * 16 + ln15;
        boff[f] = rb * 32 + ((q4 ^ ((rb >> 1) & 3)) * 8);
    }

    floatx4_t acc[4][4];
#pragma unroll
    for (int i = 0; i < 4; i++)
#pragma unroll
        for (int j = 0; j < 4; j++) acc[i][j] = (floatx4_t){0.f, 0.f, 0.f, 0.f};

    // ---- prologue: tile 0 -> buf 0 ----
    PSTAGE_A(0, 0); PSTAGE_B(0, 0);
    asm volatile("s_waitcnt vmcnt(0)" ::: "memory");
    __builtin_amdgcn_s_barrier();

    for (int T = 0; T < 32; ++T) {
        const int buf = T & 1, nb = buf ^ 1;

        bf16x8_t bfr[4], af[4];
#pragma unroll
        for (int f = 0; f < 4; f++)
            bfr[f] = *reinterpret_cast<const bf16x8_t*>(&Bs[buf][boff[f]]);
#pragma unroll
        for (int f = 0; f < 4; f++)
            af[f] = *reinterpret_cast<const bf16x8_t*>(&As[buf][aoff[f]]);

        if (T < 31) { PSTAGE_A(T + 1, nb); PSTAGE_B(T + 1, nb); }

        __builtin_amdgcn_s_setprio(1);
#pragma unroll
        for (int nf = 0; nf < 4; nf++)
#pragma unroll
            for (int mf = 0; mf < 4; mf++)
                acc[mf][nf] = __builtin_amdgcn_mfma_f32_16x16x32_bf16(
                    af[mf], bfr[nf], acc[mf][nf], 0, 0, 0);
        __builtin_amdgcn_s_setprio(0);

        asm volatile("s_waitcnt vmcnt(0)" ::: "memory");
        __builtin_amdgcn_s_barrier();
    }

    // ---- split epilogue (block-uniform region branch) ----
    const int colbase = n0 + wn * 64;
    float bv[4];
#pragma unroll
    for (int nf = 0; nf < 4; nf++) bv[nf] = bias[colbase + nf * 16 + ln15];

    const int rowb = m0 + wm * 64 + q4 * 4;   // + mf*16 + reg

    if (n0 < 1024) {
#pragma unroll
        for (int mf = 0; mf < 4; mf++)
#pragma unroll
            for (int nf = 0; nf < 4; nf++) {
                int col = colbase + nf * 16 + ln15;
#pragma unroll
                for (int reg = 0; reg < 4; reg++) {
                    int row = rowb + mf * 16 + reg;
                    Ug[(size_t)row * 1024 + col] = (__bf16)(acc[mf][nf][reg] + bv[nf]);
                }
            }
    } else if (n0 < 2048) {
        const int h = ((n0 - 1024) >> 6) + wn;    // wave spans one head
#pragma unroll
        for (int mf = 0; mf < 4; mf++)
#pragma unroll
            for (int reg = 0; reg < 4; reg++) {
                int row = rowb + mf * 16 + reg;
                int b = row >> 11, s = row & (S_ - 1);
                size_t orow = ((size_t)(b * NH + h) * S_ + s) * 64;
#pragma unroll
                for (int nf = 0; nf < 4; nf++)
                    Vh[orow + nf * 16 + ln15] = (__bf16)(acc[mf][nf][reg] + bv[nf]);
            }
    } else {
        const bool isQ = (n0 < 3072);
        const int h = ((n0 - (isQ ? 2048 : 3072)) >> 6) + wn;
        __bf16* dst = isQ ? Qh : Kh;
        const float sc = isQ ? QSCALE : 1.0f;
        // RoPE pair (d, d+32): d = nf*16+ln15 (nf=0,1), hi partner nf+2
        float inv[2];
        inv[0] = __expf(-(float)(ln15)      * ROPE_C);
        inv[1] = __expf(-(float)(16 + ln15) * ROPE_C);
#pragma unroll
        for (int mf = 0; mf < 4; mf++)
#pragma unroll
            for (int reg = 0; reg < 4; reg++) {
                int row = rowb + mf * 16 + reg;
                int b = row >> 11, s = row & (S_ - 1);
                size_t orow = ((size_t)(b * NH + h) * S_ + s) * 64;
#pragma unroll
                for (int nf = 0; nf < 2; nf++) {
                    float sn, cs;
                    __sincosf((float)s * inv[nf], &sn, &cs);
                    float lo = acc[mf][nf][reg]     + bv[nf];
                    float hi = acc[mf][nf + 2][reg] + bv[nf + 2];
                    int d = nf * 16 + ln15;
                    dst[orow + d]      = (__bf16)((lo * cs - hi * sn) * sc);
                    dst[orow + 32 + d] = (__bf16)((hi * cs + lo * sn) * sc);
                }
            }
    }
}

// ---------------------------------------------------------------------------
// out-proj GEMM: C = A @ Bt^T + bias + resid (fp32 out). 128x128, m97 struct.
// ---------------------------------------------------------------------------
__global__ __launch_bounds__(256)
void gemm_out(const __bf16* __restrict__ A, const __bf16* __restrict__ Bt,
              const float* __restrict__ bias, const float* __restrict__ resid,
              float* __restrict__ C, int M, int N, int K)
{
    __shared__ __bf16 As[128 * 32];
    __shared__ __bf16 Bs[128 * 32];

    const int tid  = threadIdx.x;
    const int wave = tid >> 6, lane = tid & 63;
    const int l31 = lane & 31, half = lane >> 5;
    const int wm = wave & 1, wn = wave >> 1;
    const int m0 = blockIdx.y * 128, n0 = blockIdx.x * 128;

    const int srow = lane >> 2;
    const int skc  = (((lane & 3) ^ ((srow >> 1) & 3)) * 8);

    const int fsw = (l31 >> 1) & 3;
    int aoff[2][2], boff[2][2];
#pragma unroll
    for (int mt = 0; mt < 2; mt++)
#pragma unroll
        for (int ks = 0; ks < 2; ks++) {
            int ra = wm * 64 + mt * 32 + l31;
            int rb = wn * 64 + mt * 32 + l31;
            int c = ks * 2 + half;
            aoff[mt][ks] = ra * 32 + ((c ^ fsw) * 8);
            boff[mt][ks] = rb * 32 + ((c ^ fsw) * 8);
        }

    floatx16_t acc[2][2];
#pragma unroll
    for (int i = 0; i < 2; i++)
#pragma unroll
        for (int j = 0; j < 2; j++) acc[i][j] = (floatx16_t)(0.f);

    for (int k0 = 0; k0 < K; k0 += 32) {
#pragma unroll
        for (int p = 0; p < 2; p++) {
            int i = wave * 2 + p;
            int rl = i * 16 + srow;
            GLOAD_LDS16(A  + (size_t)(m0 + rl) * K + k0 + skc, &As[i * 512]);
            GLOAD_LDS16(Bt + (size_t)(n0 + rl) * K + k0 + skc, &Bs[i * 512]);
        }
        __syncthreads();

        bf16x8_t af[2][2], bf[2][2];
#pragma unroll
        for (int mt = 0; mt < 2; mt++)
#pragma unroll
            for (int ks = 0; ks < 2; ks++) {
                af[mt][ks] = *reinterpret_cast<const bf16x8_t*>(&As[aoff[mt][ks]]);
                bf[mt][ks] = *reinterpret_cast<const bf16x8_t*>(&Bs[boff[mt][ks]]);
            }
#pragma unroll
        for (int ks = 0; ks < 2; ks++)
#pragma unroll
            for (int mt = 0; mt < 2; mt++)
#pragma unroll
                for (int nt = 0; nt < 2; nt++)
                    acc[mt][nt] = __builtin_amdgcn_mfma_f32_32x32x16_bf16(
                        af[mt][ks], bf[nt][ks], acc[mt][nt], 0, 0, 0);
        __syncthreads();
    }

#pragma unroll
    for (int mt = 0; mt < 2; mt++) {
#pragma unroll
        for (int nt = 0; nt < 2; nt++) {
            int col = n0 + wn * 64 + nt * 32 + l31;
            float bv = bias[col];
#pragma unroll
            for (int reg = 0; reg < 16; reg++) {
                int rowf = (reg & 3) + 8 * (reg >> 2) + 4 * half;
                int row = m0 + wm * 64 + mt * 32 + rowf;
                C[(size_t)row * N + col] = acc[mt][nt][reg] + bv + resid[(size_t)row * N + col];
            }
        }
    }
}

// ---------------------------------------------------------------------------
// V transpose: Vh[bh][s][64] -> VtG[bh][d][S]
// ---------------------------------------------------------------------------
__global__ __launch_bounds__(256)
void transpose_v(const __bf16* __restrict__ Vh, __bf16* __restrict__ VtG)
{
    const int tid = threadIdx.x;
    const int st = blockIdx.x, bh = blockIdx.y;
    const int s0 = st * 64;
    const int d = tid & 63, k16 = tid >> 6;
    __bf16 vals[16];
#pragma unroll
    for (int j = 0; j < 16; j++) {
        int k = s0 + k16 * 16 + j;
        vals[j] = Vh[((size_t)bh * S_ + k) * 64 + d];
    }
    size_t orow = ((size_t)(bh * 64 + d)) * S_ + s0 + k16 * 16;
    *reinterpret_cast<bf16x8_t*>(&VtG[orow])     = *reinterpret_cast<bf16x8_t*>(&vals[0]);
    *reinterpret_cast<bf16x8_t*>(&VtG[orow + 8]) = *reinterpret_cast<bf16x8_t*>(&vals[8]);
}

// ---------------------------------------------------------------------------
// Sigmoid attention, causal, bf16 MFMA. (R1 structure: 8 waves, one 16-row
// q-subtile per wave, qt-pairing for load balance — unchanged.)
// ---------------------------------------------------------------------------
__global__ __launch_bounds__(512, 4)
void attn_mfma(const __bf16* __restrict__ Qh, const __bf16* __restrict__ Kh,
               const __bf16* __restrict__ VtG, __bf16* __restrict__ attn_out)
{
    __shared__ __bf16 Ks[2][4096];     // 64x64 K[k][d], swizzled
    __shared__ __bf16 Vt[2][4096];     // 64x64 V^T[d][k], swizzled
    __shared__ __bf16 Ps[8][16][72];   // per-wave P strip

    const int tid = threadIdx.x, wave = tid >> 6, lane = tid & 63;
    const int quad = lane >> 4, ln = lane & 15;
    const int p  = blockIdx.x >> 6;                       // pair id 0..7
    const int hb = blockIdx.x & 63, h = hb & 15, b = hb >> 4, bh = b * NH + h;

    // staging lane constants (XOR swizzle: LDS[row][c] = global[row][c^(row&7)])
    const int sr = lane >> 3, scl = (lane & 7) ^ sr;
    const size_t khead = (size_t)bh * S_ * 64;
    const int koff = (wave * 8 + sr) * 64 + scl * 8;      // chunk = wave
    const size_t vg = ((size_t)bh * 64 + wave * 8 + sr) * S_ + scl * 8;

    // fragment LDS element offsets (kt-invariant, swizzled)
    const int m7 = ln & 7;
    int ka[4][2];
#pragma unroll
    for (int nt = 0; nt < 4; nt++) {
        int row = nt * 16 + ln;
        ka[nt][0] = row * 64 + ((quad ^ m7) << 3);
        ka[nt][1] = row * 64 + (((quad + 4) ^ m7) << 3);
    }

    const int wl   = wave * 16 + ln;   // q-row local in [0,128)
    const int wl63 = wl & 63;          // diag-mask comparand (both wave groups)
    const bool hiw = wave >= 4;

    for (int hf = 0; hf < 2; hf++) {
        const int qt = hf ? p : (15 - p);
        const int Q0 = qt * 128, T0 = 2 * qt;

        // Q fragments: loop-invariant, direct from global (one subtile, K=64)
        const size_t qr = ((size_t)bh * S_ + Q0 + wl) * 64;
        const bf16x8_t qa0 = *reinterpret_cast<const bf16x8_t*>(&Qh[qr + quad * 8]);
        const bf16x8_t qa1 = *reinterpret_cast<const bf16x8_t*>(&Qh[qr + 32 + quad * 8]);

        floatx4_t o[4];
#pragma unroll
        for (int dt = 0; dt < 4; dt++) o[dt] = (floatx4_t){0.f, 0.f, 0.f, 0.f};

        // prologue: stage kt=0 into buf 0 (safe across halves — see header)
        GLOAD_LDS16(Kh  + khead + koff, &Ks[0][wave * 512]);
        GLOAD_LDS16(VtG + vg,           &Vt[0][wave * 512]);

        for (int kt = 0; kt <= T0 + 1; kt++) {
            const int buf = kt & 1;
            __syncthreads();                 // staging of buf done; prior reads of buf^1 done
            if (kt <= T0) {                  // prefetch kt+1 into the other buffer
                const int nb = buf ^ 1;
                GLOAD_LDS16(Kh  + khead + (size_t)(kt + 1) * 4096 + koff, &Ks[nb][wave * 512]);
                GLOAD_LDS16(VtG + vg + (kt + 1) * 64,                      &Vt[nb][wave * 512]);
            }

            // mode: 0 full, 1 diag, 2 skip (fully masked)
            const int rel = kt - T0;
            const int mode = (rel < 0) ? 0 : (rel == 0 ? (hiw ? 0 : 1) : (hiw ? 1 : 2));
            if (mode == 2) continue;

            // K fragments (A for S^T)
            bf16x8_t kf[4][2];
#pragma unroll
            for (int nt = 0; nt < 4; nt++) {
                kf[nt][0] = *reinterpret_cast<const bf16x8_t*>(&Ks[buf][ka[nt][0]]);
                kf[nt][1] = *reinterpret_cast<const bf16x8_t*>(&Ks[buf][ka[nt][1]]);
            }

            // ---- S^T = K * Q^T : C-layout row=k_l, col=q_l ----
            floatx4_t st[4];
#pragma unroll
            for (int nt = 0; nt < 4; nt++) {
                floatx4_t acc = (floatx4_t){0.f, 0.f, 0.f, 0.f};
                acc = __builtin_amdgcn_mfma_f32_16x16x32_bf16(kf[nt][0], qa0, acc, 0, 0, 0);
                acc = __builtin_amdgcn_mfma_f32_16x16x32_bf16(kf[nt][1], qa1, acc, 0, 0, 0);
                st[nt] = acc;
            }

            // ---- sigmoid -> P, packed b64 writes (4 consecutive k) ----
#pragma unroll
            for (int nt = 0; nt < 4; nt++) {
                bf16x4_t pk;
#pragma unroll
                for (int r = 0; r < 4; r++) {
                    float a = st[nt][r];
                    if (mode == 1) {
                        int kl = nt * 16 + quad * 4 + r;
                        a = (kl <= wl63) ? a : __builtin_inff();  // exp2(inf)->rcp->0
                    }
                    float pv = __builtin_amdgcn_rcpf(1.f + __builtin_amdgcn_exp2f(a));
                    pk[r] = (__bf16)pv;
                }
                *reinterpret_cast<bf16x4_t*>(&Ps[wave][ln][nt * 16 + quad * 4]) = pk;
            }

            // V fragments (read late to shorten live range)
            bf16x8_t vf[4][2];
#pragma unroll
            for (int dt = 0; dt < 4; dt++) {
                vf[dt][0] = *reinterpret_cast<const bf16x8_t*>(&Vt[buf][ka[dt][0]]);
                vf[dt][1] = *reinterpret_cast<const bf16x8_t*>(&Vt[buf][ka[dt][1]]);
            }

            // ---- O += P V ----
            const __bf16* prow = &Ps[wave][ln][quad * 8];
            bf16x8_t p0 = *reinterpret_cast<const bf16x8_t*>(prow);
            bf16x8_t p1 = *reinterpret_cast<const bf16x8_t*>(prow + 32);
#pragma unroll
            for (int dt = 0; dt < 4; dt++) {
                o[dt] = __builtin_amdgcn_mfma_f32_16x16x32_bf16(p0, vf[dt][0], o[dt], 0, 0, 0);
                o[dt] = __builtin_amdgcn_mfma_f32_16x16x32_bf16(p1, vf[dt][1], o[dt], 0, 0, 0);
            }
        }

        // write attn_out[b, q, h*64+d]  (C-layout: row=quad*4+reg, col=ln)
        const int qrow_g = b * S_ + Q0 + wave * 16 + quad * 4;
#pragma unroll
        for (int dt = 0; dt < 4; dt++) {
#pragma unroll
            for (int reg = 0; reg < 4; reg++) {
                attn_out[(size_t)(qrow_g + reg) * H + h * 64 + dt * 16 + ln] =
                    (__bf16)o[dt][reg];
            }
        }
    }
}

// ---------------------------------------------------------------------------
// LayerNorm over H + SiLU(U from Ug) gating -> bf16 gated.
// ---------------------------------------------------------------------------
__global__ __launch_bounds__(256)
void ln_gate_kernel(const __bf16* __restrict__ attn_out, const __bf16* __restrict__ Ug,
                    const float* __restrict__ ln_g, const float* __restrict__ ln_b,
                    __bf16* __restrict__ gated)
{
    const int row = blockIdx.x;
    const int tid = threadIdx.x;

    bf16x4_t vb = *reinterpret_cast<const bf16x4_t*>(&attn_out[(size_t)row * H + tid * 4]);
    float v0 = (float)vb[0], v1 = (float)vb[1], v2 = (float)vb[2], v3 = (float)vb[3];
    float s  = v0 + v1 + v2 + v3;
    float sq = v0 * v0 + v1 * v1 + v2 * v2 + v3 * v3;
#pragma unroll
    for (int off = 32; off > 0; off >>= 1) {
        s  += __shfl_down(s, off);
        sq += __shfl_down(sq, off);
    }
    __shared__ float ps[4], pq[4];
    int wave = tid >> 6, lane = tid & 63;
    if (lane == 0) { ps[wave] = s; pq[wave] = sq; }
    __syncthreads();
    float ts = ps[0] + ps[1] + ps[2] + ps[3];
    float tq = pq[0] + pq[1] + pq[2] + pq[3];
    float mu  = ts * (1.f / (float)H);
    float var = tq * (1.f / (float)H) - mu * mu;
    float rstd = rsqrtf(var + 1e-8f);

    bf16x4_t ub = *reinterpret_cast<const bf16x4_t*>(&Ug[(size_t)row * 1024 + tid * 4]);
    float4 g  = *reinterpret_cast<const float4*>(&ln_g[tid * 4]);
    float4 bb = *reinterpret_cast<const float4*>(&ln_b[tid * 4]);
    float u0 = (float)ub[0], u1 = (float)ub[1], u2 = (float)ub[2], u3 = (float)ub[3];
    bf16x4_t outv;
    outv[0] = (__bf16)(((v0 - mu) * rstd * g.x + bb.x) * (u0 / (1.f + __expf(-u0))));
    outv[1] = (__bf16)(((v1 - mu) * rstd * g.y + bb.y) * (u1 / (1.f + __expf(-u1))));
    outv[2] = (__bf16)(((v2 - mu) * rstd * g.z + bb.z) * (u2 / (1.f + __expf(-u2))));
    outv[3] = (__bf16)(((v3 - mu) * rstd * g.w + bb.w) * (u3 / (1.f + __expf(-u3))));
    *reinterpret_cast<bf16x4_t*>(&gated[(size_t)row * H + tid * 4]) = outv;
}

// ---------------------------------------------------------------------------
extern "C" void kernel_launch(void* const* d_in, const int* in_sizes, int n_in,
                              void* d_out, int out_size, void* d_ws, size_t ws_size,
                              hipStream_t stream)
{
    const float* x    = (const float*)d_in[0];
    // d_in[1] = attn_mask: structurally causal tril; causality computed from indices.
    const float* Wp   = (const float*)d_in[2];
    const float* bp   = (const float*)d_in[3];
    const float* ln_g = (const float*)d_in[4];
    const float* ln_b = (const float*)d_in[5];
    const float* Wt   = (const float*)d_in[6];
    const float* bt   = (const float*)d_in[7];
    float* out = (float*)d_out;

    char* ws = (char*)d_ws;
    const size_t MB = 1024 * 1024;
    __bf16* Ug    = (__bf16*)(ws);              // 16 MB
    __bf16* Vh    = (__bf16*)(ws + 16  * MB);   // 16 MB
    __bf16* Qh    = (__bf16*)(ws + 32  * MB);   // 16 MB
    __bf16* Kh    = (__bf16*)(ws + 48  * MB);   // 16 MB
    __bf16* attn  = (__bf16*)(ws + 64  * MB);   // 16 MB
    __bf16* gated = (__bf16*)(ws + 80  * MB);   // 16 MB
    __bf16* VtG   = (__bf16*)(ws + 96  * MB);   // 16 MB
    __bf16* Ax    = (__bf16*)(ws + 112 * MB);   // 16 MB
    __bf16* Wp_t  = (__bf16*)(ws + 128 * MB);   //  8 MB
    __bf16* Wt_t  = (__bf16*)(ws + 136 * MB);   //  2 MB

    prep_kernel<<<13312, 256, 0, stream>>>(x, Wp, Wt, Ax, Wp_t, Wt_t);

    gemm_proj<<<1024, 512, 0, stream>>>(Ax, Wp_t, bp, Ug, Vh, Qh, Kh);

    transpose_v<<<dim3(S_ / 64, B_ * NH), 256, 0, stream>>>(Vh, VtG);

    attn_mfma<<<8 * B_ * NH, 512, 0, stream>>>(Qh, Kh, VtG, attn);

    ln_gate_kernel<<<ROWS, 256, 0, stream>>>(attn, Ug, ln_g, ln_b, gated);

    dim3 g3(1024 / 128, ROWS / 128);
    gemm_out<<<g3, 256, 0, stream>>>(gated, Wt_t, bt, x, out, ROWS, 1024, 1024);
}

// Round 4
// 318.780 us; speedup vs baseline: 1.0798x; 1.0021x over previous
//
#include <hip/hip_runtime.h>
#include <math.h>

#define H 1024
#define NH 16
#define HD 64
#define B_ 4
#define S_ 2048
#define ROWS (B_*S_)   // 8192

// -0.125 * log2(e): folded into Qh so sigmoid(s*0.125) = rcp(1 + exp2(dot))
#define QSCALE (-0.1803368801111664f)
#define ROPE_C (9.210340371976184f / 32.0f)   // ln(10000)/32

typedef __bf16 bf16x2_t __attribute__((ext_vector_type(2)));
typedef __bf16 bf16x4_t __attribute__((ext_vector_type(4)));
typedef __bf16 bf16x8_t __attribute__((ext_vector_type(8)));
typedef float floatx4_t __attribute__((ext_vector_type(4)));
typedef float floatx16_t __attribute__((ext_vector_type(16)));

// async global->LDS, 16B per lane, dest = wave-uniform base + lane*16
#define GLOAD_LDS16(gp, lp)                                                        \
    __builtin_amdgcn_global_load_lds(                                              \
        (const __attribute__((address_space(1))) unsigned int*)(gp),               \
        (__attribute__((address_space(3))) unsigned int*)(lp), 16, 0, 0)

// ---------------------------------------------------------------------------
// Fused prep: x->bf16 copy, Wp transpose+cvt, Wt transpose+cvt (one dispatch)
// ---------------------------------------------------------------------------
__global__ __launch_bounds__(256)
void prep_kernel(const float* __restrict__ x, const float* __restrict__ Wp,
                 const float* __restrict__ Wt,
                 __bf16* __restrict__ Ax, __bf16* __restrict__ Wp_t,
                 __bf16* __restrict__ Wt_t)
{
    __shared__ __bf16 t[32][33];
    const int flat = blockIdx.x;
    const int tid = threadIdx.x;

    if (flat < 8192) {
        size_t i = (size_t)flat * 256 + tid;
        float4 v = *reinterpret_cast<const float4*>(&x[i * 4]);
        bf16x4_t w = { (__bf16)v.x, (__bf16)v.y, (__bf16)v.z, (__bf16)v.w };
        *reinterpret_cast<bf16x4_t*>(&Ax[i * 4]) = w;
        return;
    }
    const float* W; __bf16* Wo; int K, N, bn, bk;
    if (flat < 12288) {
        int id = flat - 8192;  W = Wp; Wo = Wp_t; K = 1024; N = 4096;
        bn = (id & 127) * 32;  bk = (id >> 7) * 32;
    } else {
        int id = flat - 12288; W = Wt; Wo = Wt_t; K = 1024; N = 1024;
        bn = (id & 31) * 32;   bk = (id >> 5) * 32;
    }
    const int tx = tid & 31, ty = tid >> 5;
#pragma unroll
    for (int i = 0; i < 4; i++) {
        int r = ty + i * 8;
        t[tx][r] = (__bf16)W[(size_t)(bk + r) * N + bn + tx];
    }
    __syncthreads();
#pragma unroll
    for (int i = 0; i < 4; i++) {
        int r = ty + i * 8;
        Wo[(size_t)(bn + r) * K + bk + tx] = t[r][tx];
    }
}

// ===========================================================================
// gemm_proj R3: 128x256 tile, BK=32, 8 waves (2M x 4N), wave tile 64x64,
// 16x16x32 MFMA. 3-BUFFER RING, DEPTH-2 PREFETCH, COUNTED vmcnt(3):
// R2's per-iter vmcnt(0) drain (the regression: MfmaUtil 37.5->35.5 despite
// 2x occupancy) is replaced by T4-style counted waits — at iter T we wait
// only for tile T+1's loads (issued at T-1, ~1 full iter of latency slack);
// tile T+2's 3 loads stay in flight across the barrier.
//   iter T: ds_read tile T (buf T%3) | stage tile MIN(T+2,31) -> buf (T+2)%3
//           | 16-MFMA setprio cluster | vmcnt(3) | barrier
// Uniform 3 loads/iter via clamped dummy re-stage of tile 31 (identical
// source bytes -> race-benign; R0/R1-proven). Ring audit: buffer written at
// T holds tile T-1 whose ds_reads were consumed by T-1's MFMA before the
// T-1 end-barrier (WAR safe); per-wave vmcnt(3) before barrier => cross-wave
// visibility of tile T+1. LDS 3x24KB=72KB -> still 2 blocks/CU (144<=160).
// Swizzle unchanged from R2 (conflict-free, measured 0).
// C/D layout 16x16 (m89/m91): col=lane&15, row=(lane>>4)*4+reg.
// ===========================================================================

#define MIN31(x) ((x) < 31 ? (x) : 31)

#define PSTAGE_A(tile, nb) GLOAD_LDS16(a_src + (size_t)(tile) * 32, &As[nb][wave * 512])
#define PSTAGE_B(tile, nb) do {                                                     \
        GLOAD_LDS16(b_src0 + (size_t)(tile) * 32, &Bs[nb][wave * 512]);             \
        GLOAD_LDS16(b_src1 + (size_t)(tile) * 32, &Bs[nb][4096 + wave * 512]); } while (0)

__global__ __launch_bounds__(512, 4)
void gemm_proj(const __bf16* __restrict__ A, const __bf16* __restrict__ Bt,
               const float* __restrict__ bias,
               __bf16* __restrict__ Ug, __bf16* __restrict__ Vh,
               __bf16* __restrict__ Qh, __bf16* __restrict__ Kh)
{
    __shared__ __attribute__((aligned(16))) __bf16 As[3][128 * 32];   // 24 KB
    __shared__ __attribute__((aligned(16))) __bf16 Bs[3][256 * 32];   // 48 KB

    const int tid  = threadIdx.x;
    const int wave = tid >> 6, lane = tid & 63;
    const int ln15 = lane & 15, q4 = lane >> 4;
    const int wm = wave & 1, wn = wave >> 1;

    // XCD-contiguous bijective swizzle (1024 % 8 == 0), n-major chunks:
    // consecutive work-ids on one XCD share the B panel (L2-friendly).
    const int bid = blockIdx.x;
    const int wid = (bid & 7) * 128 + (bid >> 3);
    const int m0 = (wid & 63) * 128;
    const int n0 = (wid >> 6) * 256;

    // ---- staging constants: linear LDS dest, inverse-swizzled global src ----
    const int srow = tid >> 2;                        // 0..127
    const int csrc = (tid & 3) ^ ((tid >> 3) & 3);    // source 16B chunk
    const __bf16* a_src  = A  + (size_t)(m0 + srow) * 1024 + csrc * 8;
    const __bf16* b_src0 = Bt + (size_t)(n0 + srow) * 1024 + csrc * 8;
    const __bf16* b_src1 = b_src0 + (size_t)128 * 1024;   // rows 128..255

    // ---- fragment read offsets (elements; kt-invariant, swizzled) ----
    int aoff[4], boff[4];
#pragma unroll
    for (int f = 0; f < 4; f++) {
        int ra = wm * 64 + f * 16 + ln15;
        aoff[f] = ra * 32 + ((q4 ^ ((ra >> 1) & 3)) * 8);
        int rb = wn * 64 + f * 16 + ln15;
        boff[f] = rb * 32 + ((q4 ^ ((rb >> 1) & 3)) * 8);
    }

    floatx4_t acc[4][4];
#pragma unroll
    for (int i = 0; i < 4; i++)
#pragma unroll
        for (int j = 0; j < 4; j++) acc[i][j] = (floatx4_t){0.f, 0.f, 0.f, 0.f};

    // ---- prologue: tiles 0,1 -> bufs 0,1 (3 loads each, FIFO) ----
    PSTAGE_A(0, 0); PSTAGE_B(0, 0);
    PSTAGE_A(1, 1); PSTAGE_B(1, 1);
    asm volatile("s_waitcnt vmcnt(3)" ::: "memory");   // tile 0 landed
    __builtin_amdgcn_s_barrier();

    for (int T = 0; T < 32; ++T) {
        const int buf = T % 3, nb = (T + 2) % 3;

        bf16x8_t bfr[4], af[4];
#pragma unroll
        for (int f = 0; f < 4; f++)
            bfr[f] = *reinterpret_cast<const bf16x8_t*>(&Bs[buf][boff[f]]);
#pragma unroll
        for (int f = 0; f < 4; f++)
            af[f] = *reinterpret_cast<const bf16x8_t*>(&As[buf][aoff[f]]);

        // depth-2 prefetch: tile T+2 into the buffer vacated at iter T-1
        // (clamped dummy re-stage keeps 3 loads/iter -> uniform vmcnt)
        PSTAGE_A(MIN31(T + 2), nb); PSTAGE_B(MIN31(T + 2), nb);

        __builtin_amdgcn_s_setprio(1);
#pragma unroll
        for (int nf = 0; nf < 4; nf++)
#pragma unroll
            for (int mf = 0; mf < 4; mf++)
                acc[mf][nf] = __builtin_amdgcn_mfma_f32_16x16x32_bf16(
                    af[mf], bfr[nf], acc[mf][nf], 0, 0, 0);
        __builtin_amdgcn_s_setprio(0);

        // counted wait: tile T+1's 3 loads (issued at T-1) done; tile T+2's
        // 3 loads remain in flight across the barrier.
        asm volatile("s_waitcnt vmcnt(3)" ::: "memory");
        __builtin_amdgcn_s_barrier();
    }
    asm volatile("s_waitcnt vmcnt(0)" ::: "memory");   // drain dummy stages

    // ---- split epilogue (block-uniform region branch) ----
    const int colbase = n0 + wn * 64;
    float bv[4];
#pragma unroll
    for (int nf = 0; nf < 4; nf++) bv[nf] = bias[colbase + nf * 16 + ln15];

    const int rowb = m0 + wm * 64 + q4 * 4;   // + mf*16 + reg

    if (n0 < 1024) {
#pragma unroll
        for (int mf = 0; mf < 4; mf++)
#pragma unroll
            for (int nf = 0; nf < 4; nf++) {
                int col = colbase + nf * 16 + ln15;
#pragma unroll
                for (int reg = 0; reg < 4; reg++) {
                    int row = rowb + mf * 16 + reg;
                    Ug[(size_t)row * 1024 + col] = (__bf16)(acc[mf][nf][reg] + bv[nf]);
                }
            }
    } else if (n0 < 2048) {
        const int h = ((n0 - 1024) >> 6) + wn;    // wave spans one head
#pragma unroll
        for (int mf = 0; mf < 4; mf++)
#pragma unroll
            for (int reg = 0; reg < 4; reg++) {
                int row = rowb + mf * 16 + reg;
                int b = row >> 11, s = row & (S_ - 1);
                size_t orow = ((size_t)(b * NH + h) * S_ + s) * 64;
#pragma unroll
                for (int nf = 0; nf < 4; nf++)
                    Vh[orow + nf * 16 + ln15] = (__bf16)(acc[mf][nf][reg] + bv[nf]);
            }
    } else {
        const bool isQ = (n0 < 3072);
        const int h = ((n0 - (isQ ? 2048 : 3072)) >> 6) + wn;
        __bf16* dst = isQ ? Qh : Kh;
        const float sc = isQ ? QSCALE : 1.0f;
        // RoPE pair (d, d+32): d = nf*16+ln15 (nf=0,1), hi partner nf+2
        float inv[2];
        inv[0] = __expf(-(float)(ln15)      * ROPE_C);
        inv[1] = __expf(-(float)(16 + ln15) * ROPE_C);
#pragma unroll
        for (int mf = 0; mf < 4; mf++)
#pragma unroll
            for (int reg = 0; reg < 4; reg++) {
                int row = rowb + mf * 16 + reg;
                int b = row >> 11, s = row & (S_ - 1);
                size_t orow = ((size_t)(b * NH + h) * S_ + s) * 64;
#pragma unroll
                for (int nf = 0; nf < 2; nf++) {
                    float sn, cs;
                    __sincosf((float)s * inv[nf], &sn, &cs);
                    float lo = acc[mf][nf][reg]     + bv[nf];
                    float hi = acc[mf][nf + 2][reg] + bv[nf + 2];
                    int d = nf * 16 + ln15;
                    dst[orow + d]      = (__bf16)((lo * cs - hi * sn) * sc);
                    dst[orow + 32 + d] = (__bf16)((hi * cs + lo * sn) * sc);
                }
            }
    }
}

// ---------------------------------------------------------------------------
// out-proj GEMM: C = A @ Bt^T + bias + resid (fp32 out). 128x128, m97 struct.
// ---------------------------------------------------------------------------
__global__ __launch_bounds__(256)
void gemm_out(const __bf16* __restrict__ A, const __bf16* __restrict__ Bt,
              const float* __restrict__ bias, const float* __restrict__ resid,
              float* __restrict__ C, int M, int N, int K)
{
    __shared__ __bf16 As[128 * 32];
    __shared__ __bf16 Bs[128 * 32];

    const int tid  = threadIdx.x;
    const int wave = tid >> 6, lane = tid & 63;
    const int l31 = lane & 31, half = lane >> 5;
    const int wm = wave & 1, wn = wave >> 1;
    const int m0 = blockIdx.y * 128, n0 = blockIdx.x * 128;

    const int srow = lane >> 2;
    const int skc  = (((lane & 3) ^ ((srow >> 1) & 3)) * 8);

    const int fsw = (l31 >> 1) & 3;
    int aoff[2][2], boff[2][2];
#pragma unroll
    for (int mt = 0; mt < 2; mt++)
#pragma unroll
        for (int ks = 0; ks < 2; ks++) {
            int ra = wm * 64 + mt * 32 + l31;
            int rb = wn * 64 + mt * 32 + l31;
            int c = ks * 2 + half;
            aoff[mt][ks] = ra * 32 + ((c ^ fsw) * 8);
            boff[mt][ks] = rb * 32 + ((c ^ fsw) * 8);
        }

    floatx16_t acc[2][2];
#pragma unroll
    for (int i = 0; i < 2; i++)
#pragma unroll
        for (int j = 0; j < 2; j++) acc[i][j] = (floatx16_t)(0.f);

    for (int k0 = 0; k0 < K; k0 += 32) {
#pragma unroll
        for (int p = 0; p < 2; p++) {
            int i = wave * 2 + p;
            int rl = i * 16 + srow;
            GLOAD_LDS16(A  + (size_t)(m0 + rl) * K + k0 + skc, &As[i * 512]);
            GLOAD_LDS16(Bt + (size_t)(n0 + rl) * K + k0 + skc, &Bs[i * 512]);
        }
        __syncthreads();

        bf16x8_t af[2][2], bf[2][2];
#pragma unroll
        for (int mt = 0; mt < 2; mt++)
#pragma unroll
            for (int ks = 0; ks < 2; ks++) {
                af[mt][ks] = *reinterpret_cast<const bf16x8_t*>(&As[aoff[mt][ks]]);
                bf[mt][ks] = *reinterpret_cast<const bf16x8_t*>(&Bs[boff[mt][ks]]);
            }
#pragma unroll
        for (int ks = 0; ks < 2; ks++)
#pragma unroll
            for (int mt = 0; mt < 2; mt++)
#pragma unroll
                for (int nt = 0; nt < 2; nt++)
                    acc[mt][nt] = __builtin_amdgcn_mfma_f32_32x32x16_bf16(
                        af[mt][ks], bf[nt][ks], acc[mt][nt], 0, 0, 0);
        __syncthreads();
    }

#pragma unroll
    for (int mt = 0; mt < 2; mt++) {
#pragma unroll
        for (int nt = 0; nt < 2; nt++) {
            int col = n0 + wn * 64 + nt * 32 + l31;
            float bv = bias[col];
#pragma unroll
            for (int reg = 0; reg < 16; reg++) {
                int rowf = (reg & 3) + 8 * (reg >> 2) + 4 * half;
                int row = m0 + wm * 64 + mt * 32 + rowf;
                C[(size_t)row * N + col] = acc[mt][nt][reg] + bv + resid[(size_t)row * N + col];
            }
        }
    }
}

// ---------------------------------------------------------------------------
// V transpose: Vh[bh][s][64] -> VtG[bh][d][S]
// ---------------------------------------------------------------------------
__global__ __launch_bounds__(256)
void transpose_v(const __bf16* __restrict__ Vh, __bf16* __restrict__ VtG)
{
    const int tid = threadIdx.x;
    const int st = blockIdx.x, bh = blockIdx.y;
    const int s0 = st * 64;
    const int d = tid & 63, k16 = tid >> 6;
    __bf16 vals[16];
#pragma unroll
    for (int j = 0; j < 16; j++) {
        int k = s0 + k16 * 16 + j;
        vals[j] = Vh[((size_t)bh * S_ + k) * 64 + d];
    }
    size_t orow = ((size_t)(bh * 64 + d)) * S_ + s0 + k16 * 16;
    *reinterpret_cast<bf16x8_t*>(&VtG[orow])     = *reinterpret_cast<bf16x8_t*>(&vals[0]);
    *reinterpret_cast<bf16x8_t*>(&VtG[orow + 8]) = *reinterpret_cast<bf16x8_t*>(&vals[8]);
}

// ---------------------------------------------------------------------------
// Sigmoid attention, causal, bf16 MFMA. (R1 structure: 8 waves, one 16-row
// q-subtile per wave, qt-pairing for load balance — unchanged.)
// ---------------------------------------------------------------------------
__global__ __launch_bounds__(512, 4)
void attn_mfma(const __bf16* __restrict__ Qh, const __bf16* __restrict__ Kh,
               const __bf16* __restrict__ VtG, __bf16* __restrict__ attn_out)
{
    __shared__ __bf16 Ks[2][4096];     // 64x64 K[k][d], swizzled
    __shared__ __bf16 Vt[2][4096];     // 64x64 V^T[d][k], swizzled
    __shared__ __bf16 Ps[8][16][72];   // per-wave P strip

    const int tid = threadIdx.x, wave = tid >> 6, lane = tid & 63;
    const int quad = lane >> 4, ln = lane & 15;
    const int p  = blockIdx.x >> 6;                       // pair id 0..7
    const int hb = blockIdx.x & 63, h = hb & 15, b = hb >> 4, bh = b * NH + h;

    // staging lane constants (XOR swizzle: LDS[row][c] = global[row][c^(row&7)])
    const int sr = lane >> 3, scl = (lane & 7) ^ sr;
    const size_t khead = (size_t)bh * S_ * 64;
    const int koff = (wave * 8 + sr) * 64 + scl * 8;      // chunk = wave
    const size_t vg = ((size_t)bh * 64 + wave * 8 + sr) * S_ + scl * 8;

    // fragment LDS element offsets (kt-invariant, swizzled)
    const int m7 = ln & 7;
    int ka[4][2];
#pragma unroll
    for (int nt = 0; nt < 4; nt++) {
        int row = nt * 16 + ln;
        ka[nt][0] = row * 64 + ((quad ^ m7) << 3);
        ka[nt][1] = row * 64 + (((quad + 4) ^ m7) << 3);
    }

    const int wl   = wave * 16 + ln;   // q-row local in [0,128)
    const int wl63 = wl & 63;          // diag-mask comparand (both wave groups)
    const bool hiw = wave >= 4;

    for (int hf = 0; hf < 2; hf++) {
        const int qt = hf ? p : (15 - p);
        const int Q0 = qt * 128, T0 = 2 * qt;

        // Q fragments: loop-invariant, direct from global (one subtile, K=64)
        const size_t qr = ((size_t)bh * S_ + Q0 + wl) * 64;
        const bf16x8_t qa0 = *reinterpret_cast<const bf16x8_t*>(&Qh[qr + quad * 8]);
        const bf16x8_t qa1 = *reinterpret_cast<const bf16x8_t*>(&Qh[qr + 32 + quad * 8]);

        floatx4_t o[4];
#pragma unroll
        for (int dt = 0; dt < 4; dt++) o[dt] = (floatx4_t){0.f, 0.f, 0.f, 0.f};

        // prologue: stage kt=0 into buf 0 (safe across halves — see header)
        GLOAD_LDS16(Kh  + khead + koff, &Ks[0][wave * 512]);
        GLOAD_LDS16(VtG + vg,           &Vt[0][wave * 512]);

        for (int kt = 0; kt <= T0 + 1; kt++) {
            const int buf = kt & 1;
            __syncthreads();                 // staging of buf done; prior reads of buf^1 done
            if (kt <= T0) {                  // prefetch kt+1 into the other buffer
                const int nb = buf ^ 1;
                GLOAD_LDS16(Kh  + khead + (size_t)(kt + 1) * 4096 + koff, &Ks[nb][wave * 512]);
                GLOAD_LDS16(VtG + vg + (kt + 1) * 64,                      &Vt[nb][wave * 512]);
            }

            // mode: 0 full, 1 diag, 2 skip (fully masked)
            const int rel = kt - T0;
            const int mode = (rel < 0) ? 0 : (rel == 0 ? (hiw ? 0 : 1) : (hiw ? 1 : 2));
            if (mode == 2) continue;

            // K fragments (A for S^T)
            bf16x8_t kf[4][2];
#pragma unroll
            for (int nt = 0; nt < 4; nt++) {
                kf[nt][0] = *reinterpret_cast<const bf16x8_t*>(&Ks[buf][ka[nt][0]]);
                kf[nt][1] = *reinterpret_cast<const bf16x8_t*>(&Ks[buf][ka[nt][1]]);
            }

            // ---- S^T = K * Q^T : C-layout row=k_l, col=q_l ----
            floatx4_t st[4];
#pragma unroll
            for (int nt = 0; nt < 4; nt++) {
                floatx4_t acc = (floatx4_t){0.f, 0.f, 0.f, 0.f};
                acc = __builtin_amdgcn_mfma_f32_16x16x32_bf16(kf[nt][0], qa0, acc, 0, 0, 0);
                acc = __builtin_amdgcn_mfma_f32_16x16x32_bf16(kf[nt][1], qa1, acc, 0, 0, 0);
                st[nt] = acc;
            }

            // ---- sigmoid -> P, packed b64 writes (4 consecutive k) ----
#pragma unroll
            for (int nt = 0; nt < 4; nt++) {
                bf16x4_t pk;
#pragma unroll
                for (int r = 0; r < 4; r++) {
                    float a = st[nt][r];
                    if (mode == 1) {
                        int kl = nt * 16 + quad * 4 + r;
                        a = (kl <= wl63) ? a : __builtin_inff();  // exp2(inf)->rcp->0
                    }
                    float pv = __builtin_amdgcn_rcpf(1.f + __builtin_amdgcn_exp2f(a));
                    pk[r] = (__bf16)pv;
                }
                *reinterpret_cast<bf16x4_t*>(&Ps[wave][ln][nt * 16 + quad * 4]) = pk;
            }

            // V fragments (read late to shorten live range)
            bf16x8_t vf[4][2];
#pragma unroll
            for (int dt = 0; dt < 4; dt++) {
                vf[dt][0] = *reinterpret_cast<const bf16x8_t*>(&Vt[buf][ka[dt][0]]);
                vf[dt][1] = *reinterpret_cast<const bf16x8_t*>(&Vt[buf][ka[dt][1]]);
            }

            // ---- O += P V ----
            const __bf16* prow = &Ps[wave][ln][quad * 8];
            bf16x8_t p0 = *reinterpret_cast<const bf16x8_t*>(prow);
            bf16x8_t p1 = *reinterpret_cast<const bf16x8_t*>(prow + 32);
#pragma unroll
            for (int dt = 0; dt < 4; dt++) {
                o[dt] = __builtin_amdgcn_mfma_f32_16x16x32_bf16(p0, vf[dt][0], o[dt], 0, 0, 0);
                o[dt] = __builtin_amdgcn_mfma_f32_16x16x32_bf16(p1, vf[dt][1], o[dt], 0, 0, 0);
            }
        }

        // write attn_out[b, q, h*64+d]  (C-layout: row=quad*4+reg, col=ln)
        const int qrow_g = b * S_ + Q0 + wave * 16 + quad * 4;
#pragma unroll
        for (int dt = 0; dt < 4; dt++) {
#pragma unroll
            for (int reg = 0; reg < 4; reg++) {
                attn_out[(size_t)(qrow_g + reg) * H + h * 64 + dt * 16 + ln] =
                    (__bf16)o[dt][reg];
            }
        }
    }
}

// ---------------------------------------------------------------------------
// LayerNorm over H + SiLU(U from Ug) gating -> bf16 gated.
// ---------------------------------------------------------------------------
__global__ __launch_bounds__(256)
void ln_gate_kernel(const __bf16* __restrict__ attn_out, const __bf16* __restrict__ Ug,
                    const float* __restrict__ ln_g, const float* __restrict__ ln_b,
                    __bf16* __restrict__ gated)
{
    const int row = blockIdx.x;
    const int tid = threadIdx.x;

    bf16x4_t vb = *reinterpret_cast<const bf16x4_t*>(&attn_out[(size_t)row * H + tid * 4]);
    float v0 = (float)vb[0], v1 = (float)vb[1], v2 = (float)vb[2], v3 = (float)vb[3];
    float s  = v0 + v1 + v2 + v3;
    float sq = v0 * v0 + v1 * v1 + v2 * v2 + v3 * v3;
#pragma unroll
    for (int off = 32; off > 0; off >>= 1) {
        s  += __shfl_down(s, off);
        sq += __shfl_down(sq, off);
    }
    __shared__ float ps[4], pq[4];
    int wave = tid >> 6, lane = tid & 63;
    if (lane == 0) { ps[wave] = s; pq[wave] = sq; }
    __syncthreads();
    float ts = ps[0] + ps[1] + ps[2] + ps[3];
    float tq = pq[0] + pq[1] + pq[2] + pq[3];
    float mu  = ts * (1.f / (float)H);
    float var = tq * (1.f / (float)H) - mu * mu;
    float rstd = rsqrtf(var + 1e-8f);

    bf16x4_t ub = *reinterpret_cast<const bf16x4_t*>(&Ug[(size_t)row * 1024 + tid * 4]);
    float4 g  = *reinterpret_cast<const float4*>(&ln_g[tid * 4]);
    float4 bb = *reinterpret_cast<const float4*>(&ln_b[tid * 4]);
    float u0 = (float)ub[0], u1 = (float)ub[1], u2 = (float)ub[2], u3 = (float)ub[3];
    bf16x4_t outv;
    outv[0] = (__bf16)(((v0 - mu) * rstd * g.x + bb.x) * (u0 / (1.f + __expf(-u0))));
    outv[1] = (__bf16)(((v1 - mu) * rstd * g.y + bb.y) * (u1 / (1.f + __expf(-u1))));
    outv[2] = (__bf16)(((v2 - mu) * rstd * g.z + bb.z) * (u2 / (1.f + __expf(-u2))));
    outv[3] = (__bf16)(((v3 - mu) * rstd * g.w + bb.w) * (u3 / (1.f + __expf(-u3))));
    *reinterpret_cast<bf16x4_t*>(&gated[(size_t)row * H + tid * 4]) = outv;
}

// ---------------------------------------------------------------------------
extern "C" void kernel_launch(void* const* d_in, const int* in_sizes, int n_in,
                              void* d_out, int out_size, void* d_ws, size_t ws_size,
                              hipStream_t stream)
{
    const float* x    = (const float*)d_in[0];
    // d_in[1] = attn_mask: structurally causal tril; causality computed from indices.
    const float* Wp   = (const float*)d_in[2];
    const float* bp   = (const float*)d_in[3];
    const float* ln_g = (const float*)d_in[4];
    const float* ln_b = (const float*)d_in[5];
    const float* Wt   = (const float*)d_in[6];
    const float* bt   = (const float*)d_in[7];
    float* out = (float*)d_out;

    char* ws = (char*)d_ws;
    const size_t MB = 1024 * 1024;
    __bf16* Ug    = (__bf16*)(ws);              // 16 MB
    __bf16* Vh    = (__bf16*)(ws + 16  * MB);   // 16 MB
    __bf16* Qh    = (__bf16*)(ws + 32  * MB);   // 16 MB
    __bf16* Kh    = (__bf16*)(ws + 48  * MB);   // 16 MB
    __bf16* attn  = (__bf16*)(ws + 64  * MB);   // 16 MB
    __bf16* gated = (__bf16*)(ws + 80  * MB);   // 16 MB
    __bf16* VtG   = (__bf16*)(ws + 96  * MB);   // 16 MB
    __bf16* Ax    = (__bf16*)(ws + 112 * MB);   // 16 MB
    __bf16* Wp_t  = (__bf16*)(ws + 128 * MB);   //  8 MB
    __bf16* Wt_t  = (__bf16*)(ws + 136 * MB);   //  2 MB

    prep_kernel<<<13312, 256, 0, stream>>>(x, Wp, Wt, Ax, Wp_t, Wt_t);

    gemm_proj<<<1024, 512, 0, stream>>>(Ax, Wp_t, bp, Ug, Vh, Qh, Kh);

    transpose_v<<<dim3(S_ / 64, B_ * NH), 256, 0, stream>>>(Vh, VtG);

    attn_mfma<<<8 * B_ * NH, 512, 0, stream>>>(Qh, Kh, VtG, attn);

    ln_gate_kernel<<<ROWS, 256, 0, stream>>>(attn, Ug, ln_g, ln_b, gated);

    dim3 g3(1024 / 128, ROWS / 128);
    gemm_out<<<g3, 256, 0, stream>>>(gated, Wt_t, bt, x, out, ROWS, 1024, 1024);
}

// Round 5
// 313.575 us; speedup vs baseline: 1.0977x; 1.0166x over previous
//
#include <hip/hip_runtime.h>
#include <math.h>

#define H 1024
#define NH 16
#define HD 64
#define B_ 4
#define S_ 2048
#define ROWS (B_*S_)   // 8192

// -0.125 * log2(e): folded into Qh so sigmoid(s*0.125) = rcp(1 + exp2(dot))
#define QSCALE (-0.1803368801111664f)
#define ROPE_C (9.210340371976184f / 32.0f)   // ln(10000)/32

typedef __bf16 bf16x2_t __attribute__((ext_vector_type(2)));
typedef __bf16 bf16x4_t __attribute__((ext_vector_type(4)));
typedef __bf16 bf16x8_t __attribute__((ext_vector_type(8)));
typedef float floatx4_t __attribute__((ext_vector_type(4)));
typedef float floatx16_t __attribute__((ext_vector_type(16)));

// async global->LDS, 16B per lane, dest = wave-uniform base + lane*16
#define GLOAD_LDS16(gp, lp)                                                        \
    __builtin_amdgcn_global_load_lds(                                              \
        (const __attribute__((address_space(1))) unsigned int*)(gp),               \
        (__attribute__((address_space(3))) unsigned int*)(lp), 16, 0, 0)

// ---------------------------------------------------------------------------
// Fused prep: x->bf16 copy, Wp transpose+cvt, Wt transpose+cvt (one dispatch)
// ---------------------------------------------------------------------------
__global__ __launch_bounds__(256)
void prep_kernel(const float* __restrict__ x, const float* __restrict__ Wp,
                 const float* __restrict__ Wt,
                 __bf16* __restrict__ Ax, __bf16* __restrict__ Wp_t,
                 __bf16* __restrict__ Wt_t)
{
    __shared__ __bf16 t[32][33];
    const int flat = blockIdx.x;
    const int tid = threadIdx.x;

    if (flat < 8192) {
        size_t i = (size_t)flat * 256 + tid;
        float4 v = *reinterpret_cast<const float4*>(&x[i * 4]);
        bf16x4_t w = { (__bf16)v.x, (__bf16)v.y, (__bf16)v.z, (__bf16)v.w };
        *reinterpret_cast<bf16x4_t*>(&Ax[i * 4]) = w;
        return;
    }
    const float* W; __bf16* Wo; int K, N, bn, bk;
    if (flat < 12288) {
        int id = flat - 8192;  W = Wp; Wo = Wp_t; K = 1024; N = 4096;
        bn = (id & 127) * 32;  bk = (id >> 7) * 32;
    } else {
        int id = flat - 12288; W = Wt; Wo = Wt_t; K = 1024; N = 1024;
        bn = (id & 31) * 32;   bk = (id >> 5) * 32;
    }
    const int tx = tid & 31, ty = tid >> 5;
#pragma unroll
    for (int i = 0; i < 4; i++) {
        int r = ty + i * 8;
        t[tx][r] = (__bf16)W[(size_t)(bk + r) * N + bn + tx];
    }
    __syncthreads();
#pragma unroll
    for (int i = 0; i < 4; i++) {
        int r = ty + i * 8;
        Wo[(size_t)(bn + r) * K + bk + tx] = t[r][tx];
    }
}

// ===========================================================================
// gemm_proj (R1 version, REVERTED — session best 75.2 us, MfmaUtil 37.8%,
// conflicts 0): 256x256 tile, BK=64, 8 waves (2M x 4N), 8-phase HK schedule
// (T2 swizzle + T3/T4 counted-vmcnt + T5 setprio), 16x16x32 MFMA.
// R4 delta: XCD-contiguous bijective block swizzle only (512 % 8 == 0; each
// XCD gets 64 consecutive work-ids = 2 B-panel cols x 32 m-tiles -> 1MB
// B-panel/XCD-L2). R2/R3 restructures (co-residency at 128x256) regressed:
// acc[8][4]=128 regs makes 2-block residency impossible at 44 FLOP/LDS-byte;
// smaller tiles drop to 33 FLOP/B and go LDS-bound. Do not restructure.
//
// LDS ring (128 KiB): A slots [buf][khalf] 4 x 16KB, B likewise at +64KB.
// Phase p: buf=p>>2, sub=p&3, mh=sub&1, kk=sub>>1.
//   stage: p0 A[1][1]<-T+1 | p1 B[0][0]<-T+2 | p2 A[0][0]<-T+2
//          p3 B[0][1]<-T+2 | p4 A[0][1]<-T+2 | p5 B[1][0]<-T+3
//          p6 A[1][0]<-T+3 | p7 B[1][1]<-T+3      (T = 2*iter)
//   waits: vmcnt(6) after stage at p3/p7 only (3 half-tiles in flight).
// Swizzle: data chunk c of row r at linear chunk c ^ ((r>>1)&3) via
// inverse-permuted GLOBAL source (linear LDS dest, m104/m173).
// C/D layout 16x16 (m89/m91): col=lane&15, row=(lane>>4)*4+reg.
// ===========================================================================

#define MIN15(x) ((x) < 15 ? (x) : 15)

#define STAGE_A(buf, h, tile) do { int _kb = (tile) * 64 + (h) * 32;               \
        char* _lb = lwA + ((buf) * 2 + (h)) * 16384;                               \
        GLOAD_LDS16(a_src0 + _kb, _lb);                                            \
        GLOAD_LDS16(a_src1 + _kb, _lb + 1024); } while (0)
#define STAGE_B(buf, h, tile) do { int _kb = (tile) * 64 + (h) * 32;               \
        char* _lb = lwB + ((buf) * 2 + (h)) * 16384;                               \
        GLOAD_LDS16(b_src0 + _kb, _lb);                                            \
        GLOAD_LDS16(b_src1 + _kb, _lb + 1024); } while (0)

__global__ __launch_bounds__(512, 2)
void gemm_proj(const __bf16* __restrict__ A, const __bf16* __restrict__ Bt,
               const float* __restrict__ bias,
               __bf16* __restrict__ Ug, __bf16* __restrict__ Vh,
               __bf16* __restrict__ Qh, __bf16* __restrict__ Kh)
{
    __shared__ __attribute__((aligned(16))) char smem[131072];

    const int tid  = threadIdx.x;
    const int wave = tid >> 6, lane = tid & 63;
    const int ln15 = lane & 15, q4 = lane >> 4;
    const int wm = wave & 1, wn = wave >> 1;

    // XCD-contiguous bijective swizzle (512 % 8 == 0): XCD x gets wids
    // [x*64, x*64+64) = 2 n-cols x 32 m-tiles (B panel L2-resident).
    const int bid = blockIdx.x;
    const int wid = (bid & 7) * 64 + (bid >> 3);
    const int m0 = (wid & 31) * 256;
    const int n0 = (wid >> 5) * 256;

    // ---- staging constants: linear LDS dest, inverse-swizzled global src ----
    const int srow0 = wave * 32 + (lane >> 2);            // row for load p=0
    const int csrc  = (lane & 3) ^ ((lane >> 3) & 3);     // swizzled 16B chunk
    const __bf16* a_src0 = A  + (size_t)(m0 + srow0) * 1024 + csrc * 8;
    const __bf16* a_src1 = a_src0 + (size_t)16 * 1024;    // row +16 (load p=1)
    const __bf16* b_src0 = Bt + (size_t)(n0 + srow0) * 1024 + csrc * 8;
    const __bf16* b_src1 = b_src0 + (size_t)16 * 1024;
    char* lwA = smem + wave * 2048;                       // + slot*16384
    char* lwB = smem + 65536 + wave * 2048;

    // ---- fragment read offsets (swizzled) ----
    const int sl = (ln15 >> 1) & 3;
    const int a_lane = (wm * 128 + ln15) * 64 + ((q4 ^ sl) << 4);
    const int b_lane = (wn * 64  + ln15) * 64 + ((q4 ^ sl) << 4);

    floatx4_t acc[8][4];
#pragma unroll
    for (int i = 0; i < 8; i++)
#pragma unroll
        for (int j = 0; j < 4; j++) acc[i][j] = (floatx4_t){0.f, 0.f, 0.f, 0.f};

    // ---- prologue: T0 all 4 halves + T1 {Bk0, Ak0, Bk1}, FIFO order ----
    STAGE_B(0, 0, 0); STAGE_A(0, 0, 0); STAGE_B(0, 1, 0); STAGE_A(0, 1, 0);
    STAGE_B(1, 0, 1); STAGE_A(1, 0, 1); STAGE_B(1, 1, 1);
    asm volatile("s_waitcnt vmcnt(6)" ::: "memory");   // T0 landed
    __builtin_amdgcn_s_barrier();

    bf16x8_t bfr[4];

    for (int it = 0; it < 8; ++it) {
        const int T = 2 * it;
#pragma unroll
        for (int p = 0; p < 8; ++p) {
            const int buf = p >> 2, sub = p & 3, mh = sub & 1, kk = sub >> 1;
            const char* asl = smem + (buf * 2 + kk) * 16384;
            const char* bsl = smem + 65536 + (buf * 2 + kk) * 16384;

            // ds-loads for this phase
            if ((sub & 1) == 0) {
#pragma unroll
                for (int nf = 0; nf < 4; nf++)
                    bfr[nf] = *reinterpret_cast<const bf16x8_t*>(bsl + b_lane + nf * 1024);
            }
            bf16x8_t af[4];
#pragma unroll
            for (int mfi = 0; mfi < 4; mfi++)
                af[mfi] = *reinterpret_cast<const bf16x8_t*>(asl + a_lane + (mh * 4 + mfi) * 1024);

            // stage one half-tile
            if      (p == 0) STAGE_A(1, 1, MIN15(T + 1));
            else if (p == 1) STAGE_B(0, 0, MIN15(T + 2));
            else if (p == 2) STAGE_A(0, 0, MIN15(T + 2));
            else if (p == 3) STAGE_B(0, 1, MIN15(T + 2));
            else if (p == 4) STAGE_A(0, 1, MIN15(T + 2));
            else if (p == 5) STAGE_B(1, 0, MIN15(T + 3));
            else if (p == 6) STAGE_A(1, 0, MIN15(T + 3));
            else             STAGE_B(1, 1, MIN15(T + 3));

            if (p == 3 || p == 7)
                asm volatile("s_waitcnt vmcnt(6)" ::: "memory");
            __builtin_amdgcn_s_barrier();

            __builtin_amdgcn_s_setprio(1);
#pragma unroll
            for (int nf = 0; nf < 4; nf++)
#pragma unroll
                for (int mfi = 0; mfi < 4; mfi++)
                    acc[mh * 4 + mfi][nf] = __builtin_amdgcn_mfma_f32_16x16x32_bf16(
                        af[mfi], bfr[nf], acc[mh * 4 + mfi][nf], 0, 0, 0);
            __builtin_amdgcn_s_setprio(0);
            __builtin_amdgcn_s_barrier();
        }
    }
    asm volatile("s_waitcnt vmcnt(0)" ::: "memory");

    // ---- split epilogue (block-uniform region branch) ----
    const int colbase = n0 + wn * 64;
    float bv[4];
#pragma unroll
    for (int nf = 0; nf < 4; nf++) bv[nf] = bias[colbase + nf * 16 + ln15];

    const int rowb = m0 + wm * 128 + q4 * 4;   // + mf*16 + reg

    if (n0 < 1024) {
#pragma unroll
        for (int mf = 0; mf < 8; mf++)
#pragma unroll
            for (int nf = 0; nf < 4; nf++) {
                int col = colbase + nf * 16 + ln15;
#pragma unroll
                for (int reg = 0; reg < 4; reg++) {
                    int row = rowb + mf * 16 + reg;
                    Ug[(size_t)row * 1024 + col] = (__bf16)(acc[mf][nf][reg] + bv[nf]);
                }
            }
    } else if (n0 < 2048) {
        const int h = ((n0 - 1024) >> 6) + wn;    // wave spans one head
#pragma unroll
        for (int mf = 0; mf < 8; mf++)
#pragma unroll
            for (int reg = 0; reg < 4; reg++) {
                int row = rowb + mf * 16 + reg;
                int b = row >> 11, s = row & (S_ - 1);
                size_t orow = ((size_t)(b * NH + h) * S_ + s) * 64;
#pragma unroll
                for (int nf = 0; nf < 4; nf++)
                    Vh[orow + nf * 16 + ln15] = (__bf16)(acc[mf][nf][reg] + bv[nf]);
            }
    } else {
        const bool isQ = (n0 < 3072);
        const int h = ((n0 - (isQ ? 2048 : 3072)) >> 6) + wn;
        __bf16* dst = isQ ? Qh : Kh;
        const float sc = isQ ? QSCALE : 1.0f;
        // RoPE pair (d, d+32): d = nf*16+ln15 (nf=0,1), hi partner nf+2
        float inv[2];
        inv[0] = __expf(-(float)(ln15)      * ROPE_C);
        inv[1] = __expf(-(float)(16 + ln15) * ROPE_C);
#pragma unroll
        for (int mf = 0; mf < 8; mf++)
#pragma unroll
            for (int reg = 0; reg < 4; reg++) {
                int row = rowb + mf * 16 + reg;
                int b = row >> 11, s = row & (S_ - 1);
                size_t orow = ((size_t)(b * NH + h) * S_ + s) * 64;
#pragma unroll
                for (int nf = 0; nf < 2; nf++) {
                    float sn, cs;
                    __sincosf((float)s * inv[nf], &sn, &cs);
                    float lo = acc[mf][nf][reg]     + bv[nf];
                    float hi = acc[mf][nf + 2][reg] + bv[nf + 2];
                    int d = nf * 16 + ln15;
                    dst[orow + d]      = (__bf16)((lo * cs - hi * sn) * sc);
                    dst[orow + 32 + d] = (__bf16)((hi * cs + lo * sn) * sc);
                }
            }
    }
}

// ---------------------------------------------------------------------------
// out-proj GEMM: C = A @ Bt^T + bias + resid (fp32 out). 128x128, m97 struct.
// ---------------------------------------------------------------------------
__global__ __launch_bounds__(256)
void gemm_out(const __bf16* __restrict__ A, const __bf16* __restrict__ Bt,
              const float* __restrict__ bias, const float* __restrict__ resid,
              float* __restrict__ C, int M, int N, int K)
{
    __shared__ __bf16 As[128 * 32];
    __shared__ __bf16 Bs[128 * 32];

    const int tid  = threadIdx.x;
    const int wave = tid >> 6, lane = tid & 63;
    const int l31 = lane & 31, half = lane >> 5;
    const int wm = wave & 1, wn = wave >> 1;
    const int m0 = blockIdx.y * 128, n0 = blockIdx.x * 128;

    const int srow = lane >> 2;
    const int skc  = (((lane & 3) ^ ((srow >> 1) & 3)) * 8);

    const int fsw = (l31 >> 1) & 3;
    int aoff[2][2], boff[2][2];
#pragma unroll
    for (int mt = 0; mt < 2; mt++)
#pragma unroll
        for (int ks = 0; ks < 2; ks++) {
            int ra = wm * 64 + mt * 32 + l31;
            int rb = wn * 64 + mt * 32 + l31;
            int c = ks * 2 + half;
            aoff[mt][ks] = ra * 32 + ((c ^ fsw) * 8);
            boff[mt][ks] = rb * 32 + ((c ^ fsw) * 8);
        }

    floatx16_t acc[2][2];
#pragma unroll
    for (int i = 0; i < 2; i++)
#pragma unroll
        for (int j = 0; j < 2; j++) acc[i][j] = (floatx16_t)(0.f);

    for (int k0 = 0; k0 < K; k0 += 32) {
#pragma unroll
        for (int p = 0; p < 2; p++) {
            int i = wave * 2 + p;
            int rl = i * 16 + srow;
            GLOAD_LDS16(A  + (size_t)(m0 + rl) * K + k0 + skc, &As[i * 512]);
            GLOAD_LDS16(Bt + (size_t)(n0 + rl) * K + k0 + skc, &Bs[i * 512]);
        }
        __syncthreads();

        bf16x8_t af[2][2], bf[2][2];
#pragma unroll
        for (int mt = 0; mt < 2; mt++)
#pragma unroll
            for (int ks = 0; ks < 2; ks++) {
                af[mt][ks] = *reinterpret_cast<const bf16x8_t*>(&As[aoff[mt][ks]]);
                bf[mt][ks] = *reinterpret_cast<const bf16x8_t*>(&Bs[boff[mt][ks]]);
            }
#pragma unroll
        for (int ks = 0; ks < 2; ks++)
#pragma unroll
            for (int mt = 0; mt < 2; mt++)
#pragma unroll
                for (int nt = 0; nt < 2; nt++)
                    acc[mt][nt] = __builtin_amdgcn_mfma_f32_32x32x16_bf16(
                        af[mt][ks], bf[nt][ks], acc[mt][nt], 0, 0, 0);
        __syncthreads();
    }

#pragma unroll
    for (int mt = 0; mt < 2; mt++) {
#pragma unroll
        for (int nt = 0; nt < 2; nt++) {
            int col = n0 + wn * 64 + nt * 32 + l31;
            float bv = bias[col];
#pragma unroll
            for (int reg = 0; reg < 16; reg++) {
                int rowf = (reg & 3) + 8 * (reg >> 2) + 4 * half;
                int row = m0 + wm * 64 + mt * 32 + rowf;
                C[(size_t)row * N + col] = acc[mt][nt][reg] + bv + resid[(size_t)row * N + col];
            }
        }
    }
}

// ---------------------------------------------------------------------------
// V transpose: Vh[bh][s][64] -> VtG[bh][d][S]
// ---------------------------------------------------------------------------
__global__ __launch_bounds__(256)
void transpose_v(const __bf16* __restrict__ Vh, __bf16* __restrict__ VtG)
{
    const int tid = threadIdx.x;
    const int st = blockIdx.x, bh = blockIdx.y;
    const int s0 = st * 64;
    const int d = tid & 63, k16 = tid >> 6;
    __bf16 vals[16];
#pragma unroll
    for (int j = 0; j < 16; j++) {
        int k = s0 + k16 * 16 + j;
        vals[j] = Vh[((size_t)bh * S_ + k) * 64 + d];
    }
    size_t orow = ((size_t)(bh * 64 + d)) * S_ + s0 + k16 * 16;
    *reinterpret_cast<bf16x8_t*>(&VtG[orow])     = *reinterpret_cast<bf16x8_t*>(&vals[0]);
    *reinterpret_cast<bf16x8_t*>(&VtG[orow + 8]) = *reinterpret_cast<bf16x8_t*>(&vals[8]);
}

// ---------------------------------------------------------------------------
// Sigmoid attention, causal, bf16 MFMA. (R1 structure: 8 waves, one 16-row
// q-subtile per wave, qt-pairing for load balance.)
// R4 delta: T5 setprio(1/0) around the QK and PV MFMA clusters — attn waves
// are desynchronized (independent per-wave chains), the regime where m191
// measured +4-7%.
// ---------------------------------------------------------------------------
__global__ __launch_bounds__(512, 4)
void attn_mfma(const __bf16* __restrict__ Qh, const __bf16* __restrict__ Kh,
               const __bf16* __restrict__ VtG, __bf16* __restrict__ attn_out)
{
    __shared__ __bf16 Ks[2][4096];     // 64x64 K[k][d], swizzled
    __shared__ __bf16 Vt[2][4096];     // 64x64 V^T[d][k], swizzled
    __shared__ __bf16 Ps[8][16][72];   // per-wave P strip

    const int tid = threadIdx.x, wave = tid >> 6, lane = tid & 63;
    const int quad = lane >> 4, ln = lane & 15;
    const int p  = blockIdx.x >> 6;                       // pair id 0..7
    const int hb = blockIdx.x & 63, h = hb & 15, b = hb >> 4, bh = b * NH + h;

    // staging lane constants (XOR swizzle: LDS[row][c] = global[row][c^(row&7)])
    const int sr = lane >> 3, scl = (lane & 7) ^ sr;
    const size_t khead = (size_t)bh * S_ * 64;
    const int koff = (wave * 8 + sr) * 64 + scl * 8;      // chunk = wave
    const size_t vg = ((size_t)bh * 64 + wave * 8 + sr) * S_ + scl * 8;

    // fragment LDS element offsets (kt-invariant, swizzled)
    const int m7 = ln & 7;
    int ka[4][2];
#pragma unroll
    for (int nt = 0; nt < 4; nt++) {
        int row = nt * 16 + ln;
        ka[nt][0] = row * 64 + ((quad ^ m7) << 3);
        ka[nt][1] = row * 64 + (((quad + 4) ^ m7) << 3);
    }

    const int wl   = wave * 16 + ln;   // q-row local in [0,128)
    const int wl63 = wl & 63;          // diag-mask comparand (both wave groups)
    const bool hiw = wave >= 4;

    for (int hf = 0; hf < 2; hf++) {
        const int qt = hf ? p : (15 - p);
        const int Q0 = qt * 128, T0 = 2 * qt;

        // Q fragments: loop-invariant, direct from global (one subtile, K=64)
        const size_t qr = ((size_t)bh * S_ + Q0 + wl) * 64;
        const bf16x8_t qa0 = *reinterpret_cast<const bf16x8_t*>(&Qh[qr + quad * 8]);
        const bf16x8_t qa1 = *reinterpret_cast<const bf16x8_t*>(&Qh[qr + 32 + quad * 8]);

        floatx4_t o[4];
#pragma unroll
        for (int dt = 0; dt < 4; dt++) o[dt] = (floatx4_t){0.f, 0.f, 0.f, 0.f};

        // prologue: stage kt=0 into buf 0 (safe across halves — see header)
        GLOAD_LDS16(Kh  + khead + koff, &Ks[0][wave * 512]);
        GLOAD_LDS16(VtG + vg,           &Vt[0][wave * 512]);

        for (int kt = 0; kt <= T0 + 1; kt++) {
            const int buf = kt & 1;
            __syncthreads();                 // staging of buf done; prior reads of buf^1 done
            if (kt <= T0) {                  // prefetch kt+1 into the other buffer
                const int nb = buf ^ 1;
                GLOAD_LDS16(Kh  + khead + (size_t)(kt + 1) * 4096 + koff, &Ks[nb][wave * 512]);
                GLOAD_LDS16(VtG + vg + (kt + 1) * 64,                      &Vt[nb][wave * 512]);
            }

            // mode: 0 full, 1 diag, 2 skip (fully masked)
            const int rel = kt - T0;
            const int mode = (rel < 0) ? 0 : (rel == 0 ? (hiw ? 0 : 1) : (hiw ? 1 : 2));
            if (mode == 2) continue;

            // K fragments (A for S^T)
            bf16x8_t kf[4][2];
#pragma unroll
            for (int nt = 0; nt < 4; nt++) {
                kf[nt][0] = *reinterpret_cast<const bf16x8_t*>(&Ks[buf][ka[nt][0]]);
                kf[nt][1] = *reinterpret_cast<const bf16x8_t*>(&Ks[buf][ka[nt][1]]);
            }

            // ---- S^T = K * Q^T : C-layout row=k_l, col=q_l ----
            floatx4_t st[4];
            __builtin_amdgcn_s_setprio(1);
#pragma unroll
            for (int nt = 0; nt < 4; nt++) {
                floatx4_t acc = (floatx4_t){0.f, 0.f, 0.f, 0.f};
                acc = __builtin_amdgcn_mfma_f32_16x16x32_bf16(kf[nt][0], qa0, acc, 0, 0, 0);
                acc = __builtin_amdgcn_mfma_f32_16x16x32_bf16(kf[nt][1], qa1, acc, 0, 0, 0);
                st[nt] = acc;
            }
            __builtin_amdgcn_s_setprio(0);

            // ---- sigmoid -> P, packed b64 writes (4 consecutive k) ----
#pragma unroll
            for (int nt = 0; nt < 4; nt++) {
                bf16x4_t pk;
#pragma unroll
                for (int r = 0; r < 4; r++) {
                    float a = st[nt][r];
                    if (mode == 1) {
                        int kl = nt * 16 + quad * 4 + r;
                        a = (kl <= wl63) ? a : __builtin_inff();  // exp2(inf)->rcp->0
                    }
                    float pv = __builtin_amdgcn_rcpf(1.f + __builtin_amdgcn_exp2f(a));
                    pk[r] = (__bf16)pv;
                }
                *reinterpret_cast<bf16x4_t*>(&Ps[wave][ln][nt * 16 + quad * 4]) = pk;
            }

            // V fragments (read late to shorten live range)
            bf16x8_t vf[4][2];
#pragma unroll
            for (int dt = 0; dt < 4; dt++) {
                vf[dt][0] = *reinterpret_cast<const bf16x8_t*>(&Vt[buf][ka[dt][0]]);
                vf[dt][1] = *reinterpret_cast<const bf16x8_t*>(&Vt[buf][ka[dt][1]]);
            }

            // ---- O += P V ----
            const __bf16* prow = &Ps[wave][ln][quad * 8];
            bf16x8_t p0 = *reinterpret_cast<const bf16x8_t*>(prow);
            bf16x8_t p1 = *reinterpret_cast<const bf16x8_t*>(prow + 32);
            __builtin_amdgcn_s_setprio(1);
#pragma unroll
            for (int dt = 0; dt < 4; dt++) {
                o[dt] = __builtin_amdgcn_mfma_f32_16x16x32_bf16(p0, vf[dt][0], o[dt], 0, 0, 0);
                o[dt] = __builtin_amdgcn_mfma_f32_16x16x32_bf16(p1, vf[dt][1], o[dt], 0, 0, 0);
            }
            __builtin_amdgcn_s_setprio(0);
        }

        // write attn_out[b, q, h*64+d]  (C-layout: row=quad*4+reg, col=ln)
        const int qrow_g = b * S_ + Q0 + wave * 16 + quad * 4;
#pragma unroll
        for (int dt = 0; dt < 4; dt++) {
#pragma unroll
            for (int reg = 0; reg < 4; reg++) {
                attn_out[(size_t)(qrow_g + reg) * H + h * 64 + dt * 16 + ln] =
                    (__bf16)o[dt][reg];
            }
        }
    }
}

// ---------------------------------------------------------------------------
// LayerNorm over H + SiLU(U from Ug) gating -> bf16 gated.
// ---------------------------------------------------------------------------
__global__ __launch_bounds__(256)
void ln_gate_kernel(const __bf16* __restrict__ attn_out, const __bf16* __restrict__ Ug,
                    const float* __restrict__ ln_g, const float* __restrict__ ln_b,
                    __bf16* __restrict__ gated)
{
    const int row = blockIdx.x;
    const int tid = threadIdx.x;

    bf16x4_t vb = *reinterpret_cast<const bf16x4_t*>(&attn_out[(size_t)row * H + tid * 4]);
    float v0 = (float)vb[0], v1 = (float)vb[1], v2 = (float)vb[2], v3 = (float)vb[3];
    float s  = v0 + v1 + v2 + v3;
    float sq = v0 * v0 + v1 * v1 + v2 * v2 + v3 * v3;
#pragma unroll
    for (int off = 32; off > 0; off >>= 1) {
        s  += __shfl_down(s, off);
        sq += __shfl_down(sq, off);
    }
    __shared__ float ps[4], pq[4];
    int wave = tid >> 6, lane = tid & 63;
    if (lane == 0) { ps[wave] = s; pq[wave] = sq; }
    __syncthreads();
    float ts = ps[0] + ps[1] + ps[2] + ps[3];
    float tq = pq[0] + pq[1] + pq[2] + pq[3];
    float mu  = ts * (1.f / (float)H);
    float var = tq * (1.f / (float)H) - mu * mu;
    float rstd = rsqrtf(var + 1e-8f);

    bf16x4_t ub = *reinterpret_cast<const bf16x4_t*>(&Ug[(size_t)row * 1024 + tid * 4]);
    float4 g  = *reinterpret_cast<const float4*>(&ln_g[tid * 4]);
    float4 bb = *reinterpret_cast<const float4*>(&ln_b[tid * 4]);
    float u0 = (float)ub[0], u1 = (float)ub[1], u2 = (float)ub[2], u3 = (float)ub[3];
    bf16x4_t outv;
    outv[0] = (__bf16)(((v0 - mu) * rstd * g.x + bb.x) * (u0 / (1.f + __expf(-u0))));
    outv[1] = (__bf16)(((v1 - mu) * rstd * g.y + bb.y) * (u1 / (1.f + __expf(-u1))));
    outv[2] = (__bf16)(((v2 - mu) * rstd * g.z + bb.z) * (u2 / (1.f + __expf(-u2))));
    outv[3] = (__bf16)(((v3 - mu) * rstd * g.w + bb.w) * (u3 / (1.f + __expf(-u3))));
    *reinterpret_cast<bf16x4_t*>(&gated[(size_t)row * H + tid * 4]) = outv;
}

// ---------------------------------------------------------------------------
extern "C" void kernel_launch(void* const* d_in, const int* in_sizes, int n_in,
                              void* d_out, int out_size, void* d_ws, size_t ws_size,
                              hipStream_t stream)
{
    const float* x    = (const float*)d_in[0];
    // d_in[1] = attn_mask: structurally causal tril; causality computed from indices.
    const float* Wp   = (const float*)d_in[2];
    const float* bp   = (const float*)d_in[3];
    const float* ln_g = (const float*)d_in[4];
    const float* ln_b = (const float*)d_in[5];
    const float* Wt   = (const float*)d_in[6];
    const float* bt   = (const float*)d_in[7];
    float* out = (float*)d_out;

    char* ws = (char*)d_ws;
    const size_t MB = 1024 * 1024;
    __bf16* Ug    = (__bf16*)(ws);              // 16 MB
    __bf16* Vh    = (__bf16*)(ws + 16  * MB);   // 16 MB
    __bf16* Qh    = (__bf16*)(ws + 32  * MB);   // 16 MB
    __bf16* Kh    = (__bf16*)(ws + 48  * MB);   // 16 MB
    __bf16* attn  = (__bf16*)(ws + 64  * MB);   // 16 MB
    __bf16* gated = (__bf16*)(ws + 80  * MB);   // 16 MB
    __bf16* VtG   = (__bf16*)(ws + 96  * MB);   // 16 MB
    __bf16* Ax    = (__bf16*)(ws + 112 * MB);   // 16 MB
    __bf16* Wp_t  = (__bf16*)(ws + 128 * MB);   //  8 MB
    __bf16* Wt_t  = (__bf16*)(ws + 136 * MB);   //  2 MB

    prep_kernel<<<13312, 256, 0, stream>>>(x, Wp, Wt, Ax, Wp_t, Wt_t);

    gemm_proj<<<512, 512, 0, stream>>>(Ax, Wp_t, bp, Ug, Vh, Qh, Kh);

    transpose_v<<<dim3(S_ / 64, B_ * NH), 256, 0, stream>>>(Vh, VtG);

    attn_mfma<<<8 * B_ * NH, 512, 0, stream>>>(Qh, Kh, VtG, attn);

    ln_gate_kernel<<<ROWS, 256, 0, stream>>>(attn, Ug, ln_g, ln_b, gated);

    dim3 g3(1024 / 128, ROWS / 128);
    gemm_out<<<g3, 256, 0, stream>>>(gated, Wt_t, bt, x, out, ROWS, 1024, 1024);
}

// Round 6
// 309.570 us; speedup vs baseline: 1.1119x; 1.0129x over previous
//
#include <hip/hip_runtime.h>
#include <math.h>

#define H 1024
#define NH 16
#define HD 64
#define B_ 4
#define S_ 2048
#define ROWS (B_*S_)   // 8192

// -0.125 * log2(e): folded into Qh so sigmoid(s*0.125) = rcp(1 + exp2(dot))
#define QSCALE (-0.1803368801111664f)
#define ROPE_C (9.210340371976184f / 32.0f)   // ln(10000)/32

typedef __bf16 bf16x2_t __attribute__((ext_vector_type(2)));
typedef __bf16 bf16x4_t __attribute__((ext_vector_type(4)));
typedef __bf16 bf16x8_t __attribute__((ext_vector_type(8)));
typedef float floatx4_t __attribute__((ext_vector_type(4)));
typedef float floatx16_t __attribute__((ext_vector_type(16)));

// async global->LDS, 16B per lane, dest = wave-uniform base + lane*16
#define GLOAD_LDS16(gp, lp)                                                        \
    __builtin_amdgcn_global_load_lds(                                              \
        (const __attribute__((address_space(1))) unsigned int*)(gp),               \
        (__attribute__((address_space(3))) unsigned int*)(lp), 16, 0, 0)

// ---------------------------------------------------------------------------
// Fused prep: x->bf16 copy, Wp transpose+cvt, Wt transpose+cvt (one dispatch)
// ---------------------------------------------------------------------------
__global__ __launch_bounds__(256)
void prep_kernel(const float* __restrict__ x, const float* __restrict__ Wp,
                 const float* __restrict__ Wt,
                 __bf16* __restrict__ Ax, __bf16* __restrict__ Wp_t,
                 __bf16* __restrict__ Wt_t)
{
    __shared__ __bf16 t[32][33];
    const int flat = blockIdx.x;
    const int tid = threadIdx.x;

    if (flat < 8192) {
        size_t i = (size_t)flat * 256 + tid;
        float4 v = *reinterpret_cast<const float4*>(&x[i * 4]);
        bf16x4_t w = { (__bf16)v.x, (__bf16)v.y, (__bf16)v.z, (__bf16)v.w };
        *reinterpret_cast<bf16x4_t*>(&Ax[i * 4]) = w;
        return;
    }
    const float* W; __bf16* Wo; int K, N, bn, bk;
    if (flat < 12288) {
        int id = flat - 8192;  W = Wp; Wo = Wp_t; K = 1024; N = 4096;
        bn = (id & 127) * 32;  bk = (id >> 7) * 32;
    } else {
        int id = flat - 12288; W = Wt; Wo = Wt_t; K = 1024; N = 1024;
        bn = (id & 31) * 32;   bk = (id >> 5) * 32;
    }
    const int tx = tid & 31, ty = tid >> 5;
#pragma unroll
    for (int i = 0; i < 4; i++) {
        int r = ty + i * 8;
        t[tx][r] = (__bf16)W[(size_t)(bk + r) * N + bn + tx];
    }
    __syncthreads();
#pragma unroll
    for (int i = 0; i < 4; i++) {
        int r = ty + i * 8;
        Wo[(size_t)(bn + r) * K + bk + tx] = t[r][tx];
    }
}

// ===========================================================================
// gemm_proj (R1 version, fully restored — session best 75.2 us, MfmaUtil
// 37.8%, FETCH 73.9MB, conflicts 0): 256x256 tile, BK=64, 8 waves (2M x 4N),
// 8-phase HK schedule (T2 swizzle + T3/T4 counted-vmcnt + T5 setprio),
// 16x16x32 MFMA. 2D grid, DEFAULT dispatch order (x-major): 16 consecutive
// n-blocks share one 512KB A-panel row — measured-better L2 schedule than
// the R4 XCD swizzle (which made every XCD stream all of A: FETCH 135MB,
// +7us; reverted). R2/R3 small-tile co-residency restructures also
// regressed (LDS-intensity drops to 33 FLOP/B). Do not restructure.
//
// LDS ring (128 KiB): A slots [buf][khalf] 4 x 16KB, B likewise at +64KB.
// Phase p: buf=p>>2, sub=p&3, mh=sub&1, kk=sub>>1.
//   stage: p0 A[1][1]<-T+1 | p1 B[0][0]<-T+2 | p2 A[0][0]<-T+2
//          p3 B[0][1]<-T+2 | p4 A[0][1]<-T+2 | p5 B[1][0]<-T+3
//          p6 A[1][0]<-T+3 | p7 B[1][1]<-T+3      (T = 2*iter)
//   waits: vmcnt(6) after stage at p3/p7 only (3 half-tiles in flight).
// Swizzle: data chunk c of row r at linear chunk c ^ ((r>>1)&3) via
// inverse-permuted GLOBAL source (linear LDS dest, m104/m173).
// C/D layout 16x16 (m89/m91): col=lane&15, row=(lane>>4)*4+reg.
// ===========================================================================

#define MIN15(x) ((x) < 15 ? (x) : 15)

#define STAGE_A(buf, h, tile) do { int _kb = (tile) * 64 + (h) * 32;               \
        char* _lb = lwA + ((buf) * 2 + (h)) * 16384;                               \
        GLOAD_LDS16(a_src0 + _kb, _lb);                                            \
        GLOAD_LDS16(a_src1 + _kb, _lb + 1024); } while (0)
#define STAGE_B(buf, h, tile) do { int _kb = (tile) * 64 + (h) * 32;               \
        char* _lb = lwB + ((buf) * 2 + (h)) * 16384;                               \
        GLOAD_LDS16(b_src0 + _kb, _lb);                                            \
        GLOAD_LDS16(b_src1 + _kb, _lb + 1024); } while (0)

__global__ __launch_bounds__(512, 2)
void gemm_proj(const __bf16* __restrict__ A, const __bf16* __restrict__ Bt,
               const float* __restrict__ bias,
               __bf16* __restrict__ Ug, __bf16* __restrict__ Vh,
               __bf16* __restrict__ Qh, __bf16* __restrict__ Kh)
{
    __shared__ __attribute__((aligned(16))) char smem[131072];

    const int tid  = threadIdx.x;
    const int wave = tid >> 6, lane = tid & 63;
    const int ln15 = lane & 15, q4 = lane >> 4;
    const int wm = wave & 1, wn = wave >> 1;
    const int m0 = blockIdx.y * 256, n0 = blockIdx.x * 256;

    // ---- staging constants: linear LDS dest, inverse-swizzled global src ----
    const int srow0 = wave * 32 + (lane >> 2);            // row for load p=0
    const int csrc  = (lane & 3) ^ ((lane >> 3) & 3);     // swizzled 16B chunk
    const __bf16* a_src0 = A  + (size_t)(m0 + srow0) * 1024 + csrc * 8;
    const __bf16* a_src1 = a_src0 + (size_t)16 * 1024;    // row +16 (load p=1)
    const __bf16* b_src0 = Bt + (size_t)(n0 + srow0) * 1024 + csrc * 8;
    const __bf16* b_src1 = b_src0 + (size_t)16 * 1024;
    char* lwA = smem + wave * 2048;                       // + slot*16384
    char* lwB = smem + 65536 + wave * 2048;

    // ---- fragment read offsets (swizzled) ----
    const int sl = (ln15 >> 1) & 3;
    const int a_lane = (wm * 128 + ln15) * 64 + ((q4 ^ sl) << 4);
    const int b_lane = (wn * 64  + ln15) * 64 + ((q4 ^ sl) << 4);

    floatx4_t acc[8][4];
#pragma unroll
    for (int i = 0; i < 8; i++)
#pragma unroll
        for (int j = 0; j < 4; j++) acc[i][j] = (floatx4_t){0.f, 0.f, 0.f, 0.f};

    // ---- prologue: T0 all 4 halves + T1 {Bk0, Ak0, Bk1}, FIFO order ----
    STAGE_B(0, 0, 0); STAGE_A(0, 0, 0); STAGE_B(0, 1, 0); STAGE_A(0, 1, 0);
    STAGE_B(1, 0, 1); STAGE_A(1, 0, 1); STAGE_B(1, 1, 1);
    asm volatile("s_waitcnt vmcnt(6)" ::: "memory");   // T0 landed
    __builtin_amdgcn_s_barrier();

    bf16x8_t bfr[4];

    for (int it = 0; it < 8; ++it) {
        const int T = 2 * it;
#pragma unroll
        for (int p = 0; p < 8; ++p) {
            const int buf = p >> 2, sub = p & 3, mh = sub & 1, kk = sub >> 1;
            const char* asl = smem + (buf * 2 + kk) * 16384;
            const char* bsl = smem + 65536 + (buf * 2 + kk) * 16384;

            // ds-loads for this phase
            if ((sub & 1) == 0) {
#pragma unroll
                for (int nf = 0; nf < 4; nf++)
                    bfr[nf] = *reinterpret_cast<const bf16x8_t*>(bsl + b_lane + nf * 1024);
            }
            bf16x8_t af[4];
#pragma unroll
            for (int mfi = 0; mfi < 4; mfi++)
                af[mfi] = *reinterpret_cast<const bf16x8_t*>(asl + a_lane + (mh * 4 + mfi) * 1024);

            // stage one half-tile
            if      (p == 0) STAGE_A(1, 1, MIN15(T + 1));
            else if (p == 1) STAGE_B(0, 0, MIN15(T + 2));
            else if (p == 2) STAGE_A(0, 0, MIN15(T + 2));
            else if (p == 3) STAGE_B(0, 1, MIN15(T + 2));
            else if (p == 4) STAGE_A(0, 1, MIN15(T + 2));
            else if (p == 5) STAGE_B(1, 0, MIN15(T + 3));
            else if (p == 6) STAGE_A(1, 0, MIN15(T + 3));
            else             STAGE_B(1, 1, MIN15(T + 3));

            if (p == 3 || p == 7)
                asm volatile("s_waitcnt vmcnt(6)" ::: "memory");
            __builtin_amdgcn_s_barrier();

            __builtin_amdgcn_s_setprio(1);
#pragma unroll
            for (int nf = 0; nf < 4; nf++)
#pragma unroll
                for (int mfi = 0; mfi < 4; mfi++)
                    acc[mh * 4 + mfi][nf] = __builtin_amdgcn_mfma_f32_16x16x32_bf16(
                        af[mfi], bfr[nf], acc[mh * 4 + mfi][nf], 0, 0, 0);
            __builtin_amdgcn_s_setprio(0);
            __builtin_amdgcn_s_barrier();
        }
    }
    asm volatile("s_waitcnt vmcnt(0)" ::: "memory");

    // ---- split epilogue (block-uniform region branch) ----
    const int colbase = n0 + wn * 64;
    float bv[4];
#pragma unroll
    for (int nf = 0; nf < 4; nf++) bv[nf] = bias[colbase + nf * 16 + ln15];

    const int rowb = m0 + wm * 128 + q4 * 4;   // + mf*16 + reg

    if (n0 < 1024) {
#pragma unroll
        for (int mf = 0; mf < 8; mf++)
#pragma unroll
            for (int nf = 0; nf < 4; nf++) {
                int col = colbase + nf * 16 + ln15;
#pragma unroll
                for (int reg = 0; reg < 4; reg++) {
                    int row = rowb + mf * 16 + reg;
                    Ug[(size_t)row * 1024 + col] = (__bf16)(acc[mf][nf][reg] + bv[nf]);
                }
            }
    } else if (n0 < 2048) {
        const int h = ((n0 - 1024) >> 6) + wn;    // wave spans one head
#pragma unroll
        for (int mf = 0; mf < 8; mf++)
#pragma unroll
            for (int reg = 0; reg < 4; reg++) {
                int row = rowb + mf * 16 + reg;
                int b = row >> 11, s = row & (S_ - 1);
                size_t orow = ((size_t)(b * NH + h) * S_ + s) * 64;
#pragma unroll
                for (int nf = 0; nf < 4; nf++)
                    Vh[orow + nf * 16 + ln15] = (__bf16)(acc[mf][nf][reg] + bv[nf]);
            }
    } else {
        const bool isQ = (n0 < 3072);
        const int h = ((n0 - (isQ ? 2048 : 3072)) >> 6) + wn;
        __bf16* dst = isQ ? Qh : Kh;
        const float sc = isQ ? QSCALE : 1.0f;
        // RoPE pair (d, d+32): d = nf*16+ln15 (nf=0,1), hi partner nf+2
        float inv[2];
        inv[0] = __expf(-(float)(ln15)      * ROPE_C);
        inv[1] = __expf(-(float)(16 + ln15) * ROPE_C);
#pragma unroll
        for (int mf = 0; mf < 8; mf++)
#pragma unroll
            for (int reg = 0; reg < 4; reg++) {
                int row = rowb + mf * 16 + reg;
                int b = row >> 11, s = row & (S_ - 1);
                size_t orow = ((size_t)(b * NH + h) * S_ + s) * 64;
#pragma unroll
                for (int nf = 0; nf < 2; nf++) {
                    float sn, cs;
                    __sincosf((float)s * inv[nf], &sn, &cs);
                    float lo = acc[mf][nf][reg]     + bv[nf];
                    float hi = acc[mf][nf + 2][reg] + bv[nf + 2];
                    int d = nf * 16 + ln15;
                    dst[orow + d]      = (__bf16)((lo * cs - hi * sn) * sc);
                    dst[orow + 32 + d] = (__bf16)((hi * cs + lo * sn) * sc);
                }
            }
    }
}

// ---------------------------------------------------------------------------
// out-proj GEMM: C = A @ Bt^T + bias + resid (fp32 out). 128x128, m97 struct.
// ---------------------------------------------------------------------------
__global__ __launch_bounds__(256)
void gemm_out(const __bf16* __restrict__ A, const __bf16* __restrict__ Bt,
              const float* __restrict__ bias, const float* __restrict__ resid,
              float* __restrict__ C, int M, int N, int K)
{
    __shared__ __bf16 As[128 * 32];
    __shared__ __bf16 Bs[128 * 32];

    const int tid  = threadIdx.x;
    const int wave = tid >> 6, lane = tid & 63;
    const int l31 = lane & 31, half = lane >> 5;
    const int wm = wave & 1, wn = wave >> 1;
    const int m0 = blockIdx.y * 128, n0 = blockIdx.x * 128;

    const int srow = lane >> 2;
    const int skc  = (((lane & 3) ^ ((srow >> 1) & 3)) * 8);

    const int fsw = (l31 >> 1) & 3;
    int aoff[2][2], boff[2][2];
#pragma unroll
    for (int mt = 0; mt < 2; mt++)
#pragma unroll
        for (int ks = 0; ks < 2; ks++) {
            int ra = wm * 64 + mt * 32 + l31;
            int rb = wn * 64 + mt * 32 + l31;
            int c = ks * 2 + half;
            aoff[mt][ks] = ra * 32 + ((c ^ fsw) * 8);
            boff[mt][ks] = rb * 32 + ((c ^ fsw) * 8);
        }

    floatx16_t acc[2][2];
#pragma unroll
    for (int i = 0; i < 2; i++)
#pragma unroll
        for (int j = 0; j < 2; j++) acc[i][j] = (floatx16_t)(0.f);

    for (int k0 = 0; k0 < K; k0 += 32) {
#pragma unroll
        for (int p = 0; p < 2; p++) {
            int i = wave * 2 + p;
            int rl = i * 16 + srow;
            GLOAD_LDS16(A  + (size_t)(m0 + rl) * K + k0 + skc, &As[i * 512]);
            GLOAD_LDS16(Bt + (size_t)(n0 + rl) * K + k0 + skc, &Bs[i * 512]);
        }
        __syncthreads();

        bf16x8_t af[2][2], bf[2][2];
#pragma unroll
        for (int mt = 0; mt < 2; mt++)
#pragma unroll
            for (int ks = 0; ks < 2; ks++) {
                af[mt][ks] = *reinterpret_cast<const bf16x8_t*>(&As[aoff[mt][ks]]);
                bf[mt][ks] = *reinterpret_cast<const bf16x8_t*>(&Bs[boff[mt][ks]]);
            }
#pragma unroll
        for (int ks = 0; ks < 2; ks++)
#pragma unroll
            for (int mt = 0; mt < 2; mt++)
#pragma unroll
                for (int nt = 0; nt < 2; nt++)
                    acc[mt][nt] = __builtin_amdgcn_mfma_f32_32x32x16_bf16(
                        af[mt][ks], bf[nt][ks], acc[mt][nt], 0, 0, 0);
        __syncthreads();
    }

#pragma unroll
    for (int mt = 0; mt < 2; mt++) {
#pragma unroll
        for (int nt = 0; nt < 2; nt++) {
            int col = n0 + wn * 64 + nt * 32 + l31;
            float bv = bias[col];
#pragma unroll
            for (int reg = 0; reg < 16; reg++) {
                int rowf = (reg & 3) + 8 * (reg >> 2) + 4 * half;
                int row = m0 + wm * 64 + mt * 32 + rowf;
                C[(size_t)row * N + col] = acc[mt][nt][reg] + bv + resid[(size_t)row * N + col];
            }
        }
    }
}

// ---------------------------------------------------------------------------
// V transpose: Vh[bh][s][64] -> VtG[bh][d][S]
// ---------------------------------------------------------------------------
__global__ __launch_bounds__(256)
void transpose_v(const __bf16* __restrict__ Vh, __bf16* __restrict__ VtG)
{
    const int tid = threadIdx.x;
    const int st = blockIdx.x, bh = blockIdx.y;
    const int s0 = st * 64;
    const int d = tid & 63, k16 = tid >> 6;
    __bf16 vals[16];
#pragma unroll
    for (int j = 0; j < 16; j++) {
        int k = s0 + k16 * 16 + j;
        vals[j] = Vh[((size_t)bh * S_ + k) * 64 + d];
    }
    size_t orow = ((size_t)(bh * 64 + d)) * S_ + s0 + k16 * 16;
    *reinterpret_cast<bf16x8_t*>(&VtG[orow])     = *reinterpret_cast<bf16x8_t*>(&vals[0]);
    *reinterpret_cast<bf16x8_t*>(&VtG[orow + 8]) = *reinterpret_cast<bf16x8_t*>(&vals[8]);
}

// ---------------------------------------------------------------------------
// Sigmoid attention, causal, bf16 MFMA. (R1 structure: 8 waves, one 16-row
// q-subtile per wave, qt-pairing for load balance; R4's T5 setprio around
// QK and PV MFMA clusters kept — attributed ~+6us of R4's total gain.)
// ---------------------------------------------------------------------------
__global__ __launch_bounds__(512, 4)
void attn_mfma(const __bf16* __restrict__ Qh, const __bf16* __restrict__ Kh,
               const __bf16* __restrict__ VtG, __bf16* __restrict__ attn_out)
{
    __shared__ __bf16 Ks[2][4096];     // 64x64 K[k][d], swizzled
    __shared__ __bf16 Vt[2][4096];     // 64x64 V^T[d][k], swizzled
    __shared__ __bf16 Ps[8][16][72];   // per-wave P strip

    const int tid = threadIdx.x, wave = tid >> 6, lane = tid & 63;
    const int quad = lane >> 4, ln = lane & 15;
    const int p  = blockIdx.x >> 6;                       // pair id 0..7
    const int hb = blockIdx.x & 63, h = hb & 15, b = hb >> 4, bh = b * NH + h;

    // staging lane constants (XOR swizzle: LDS[row][c] = global[row][c^(row&7)])
    const int sr = lane >> 3, scl = (lane & 7) ^ sr;
    const size_t khead = (size_t)bh * S_ * 64;
    const int koff = (wave * 8 + sr) * 64 + scl * 8;      // chunk = wave
    const size_t vg = ((size_t)bh * 64 + wave * 8 + sr) * S_ + scl * 8;

    // fragment LDS element offsets (kt-invariant, swizzled)
    const int m7 = ln & 7;
    int ka[4][2];
#pragma unroll
    for (int nt = 0; nt < 4; nt++) {
        int row = nt * 16 + ln;
        ka[nt][0] = row * 64 + ((quad ^ m7) << 3);
        ka[nt][1] = row * 64 + (((quad + 4) ^ m7) << 3);
    }

    const int wl   = wave * 16 + ln;   // q-row local in [0,128)
    const int wl63 = wl & 63;          // diag-mask comparand (both wave groups)
    const bool hiw = wave >= 4;

    for (int hf = 0; hf < 2; hf++) {
        const int qt = hf ? p : (15 - p);
        const int Q0 = qt * 128, T0 = 2 * qt;

        // Q fragments: loop-invariant, direct from global (one subtile, K=64)
        const size_t qr = ((size_t)bh * S_ + Q0 + wl) * 64;
        const bf16x8_t qa0 = *reinterpret_cast<const bf16x8_t*>(&Qh[qr + quad * 8]);
        const bf16x8_t qa1 = *reinterpret_cast<const bf16x8_t*>(&Qh[qr + 32 + quad * 8]);

        floatx4_t o[4];
#pragma unroll
        for (int dt = 0; dt < 4; dt++) o[dt] = (floatx4_t){0.f, 0.f, 0.f, 0.f};

        // prologue: stage kt=0 into buf 0 (safe across halves — see header)
        GLOAD_LDS16(Kh  + khead + koff, &Ks[0][wave * 512]);
        GLOAD_LDS16(VtG + vg,           &Vt[0][wave * 512]);

        for (int kt = 0; kt <= T0 + 1; kt++) {
            const int buf = kt & 1;
            __syncthreads();                 // staging of buf done; prior reads of buf^1 done
            if (kt <= T0) {                  // prefetch kt+1 into the other buffer
                const int nb = buf ^ 1;
                GLOAD_LDS16(Kh  + khead + (size_t)(kt + 1) * 4096 + koff, &Ks[nb][wave * 512]);
                GLOAD_LDS16(VtG + vg + (kt + 1) * 64,                      &Vt[nb][wave * 512]);
            }

            // mode: 0 full, 1 diag, 2 skip (fully masked)
            const int rel = kt - T0;
            const int mode = (rel < 0) ? 0 : (rel == 0 ? (hiw ? 0 : 1) : (hiw ? 1 : 2));
            if (mode == 2) continue;

            // K fragments (A for S^T)
            bf16x8_t kf[4][2];
#pragma unroll
            for (int nt = 0; nt < 4; nt++) {
                kf[nt][0] = *reinterpret_cast<const bf16x8_t*>(&Ks[buf][ka[nt][0]]);
                kf[nt][1] = *reinterpret_cast<const bf16x8_t*>(&Ks[buf][ka[nt][1]]);
            }

            // ---- S^T = K * Q^T : C-layout row=k_l, col=q_l ----
            floatx4_t st[4];
            __builtin_amdgcn_s_setprio(1);
#pragma unroll
            for (int nt = 0; nt < 4; nt++) {
                floatx4_t acc = (floatx4_t){0.f, 0.f, 0.f, 0.f};
                acc = __builtin_amdgcn_mfma_f32_16x16x32_bf16(kf[nt][0], qa0, acc, 0, 0, 0);
                acc = __builtin_amdgcn_mfma_f32_16x16x32_bf16(kf[nt][1], qa1, acc, 0, 0, 0);
                st[nt] = acc;
            }
            __builtin_amdgcn_s_setprio(0);

            // ---- sigmoid -> P, packed b64 writes (4 consecutive k) ----
#pragma unroll
            for (int nt = 0; nt < 4; nt++) {
                bf16x4_t pk;
#pragma unroll
                for (int r = 0; r < 4; r++) {
                    float a = st[nt][r];
                    if (mode == 1) {
                        int kl = nt * 16 + quad * 4 + r;
                        a = (kl <= wl63) ? a : __builtin_inff();  // exp2(inf)->rcp->0
                    }
                    float pv = __builtin_amdgcn_rcpf(1.f + __builtin_amdgcn_exp2f(a));
                    pk[r] = (__bf16)pv;
                }
                *reinterpret_cast<bf16x4_t*>(&Ps[wave][ln][nt * 16 + quad * 4]) = pk;
            }

            // V fragments (read late to shorten live range)
            bf16x8_t vf[4][2];
#pragma unroll
            for (int dt = 0; dt < 4; dt++) {
                vf[dt][0] = *reinterpret_cast<const bf16x8_t*>(&Vt[buf][ka[dt][0]]);
                vf[dt][1] = *reinterpret_cast<const bf16x8_t*>(&Vt[buf][ka[dt][1]]);
            }

            // ---- O += P V ----
            const __bf16* prow = &Ps[wave][ln][quad * 8];
            bf16x8_t p0 = *reinterpret_cast<const bf16x8_t*>(prow);
            bf16x8_t p1 = *reinterpret_cast<const bf16x8_t*>(prow + 32);
            __builtin_amdgcn_s_setprio(1);
#pragma unroll
            for (int dt = 0; dt < 4; dt++) {
                o[dt] = __builtin_amdgcn_mfma_f32_16x16x32_bf16(p0, vf[dt][0], o[dt], 0, 0, 0);
                o[dt] = __builtin_amdgcn_mfma_f32_16x16x32_bf16(p1, vf[dt][1], o[dt], 0, 0, 0);
            }
            __builtin_amdgcn_s_setprio(0);
        }

        // write attn_out[b, q, h*64+d]  (C-layout: row=quad*4+reg, col=ln)
        const int qrow_g = b * S_ + Q0 + wave * 16 + quad * 4;
#pragma unroll
        for (int dt = 0; dt < 4; dt++) {
#pragma unroll
            for (int reg = 0; reg < 4; reg++) {
                attn_out[(size_t)(qrow_g + reg) * H + h * 64 + dt * 16 + ln] =
                    (__bf16)o[dt][reg];
            }
        }
    }
}

// ---------------------------------------------------------------------------
// LayerNorm over H + SiLU(U from Ug) gating -> bf16 gated.
// ---------------------------------------------------------------------------
__global__ __launch_bounds__(256)
void ln_gate_kernel(const __bf16* __restrict__ attn_out, const __bf16* __restrict__ Ug,
                    const float* __restrict__ ln_g, const float* __restrict__ ln_b,
                    __bf16* __restrict__ gated)
{
    const int row = blockIdx.x;
    const int tid = threadIdx.x;

    bf16x4_t vb = *reinterpret_cast<const bf16x4_t*>(&attn_out[(size_t)row * H + tid * 4]);
    float v0 = (float)vb[0], v1 = (float)vb[1], v2 = (float)vb[2], v3 = (float)vb[3];
    float s  = v0 + v1 + v2 + v3;
    float sq = v0 * v0 + v1 * v1 + v2 * v2 + v3 * v3;
#pragma unroll
    for (int off = 32; off > 0; off >>= 1) {
        s  += __shfl_down(s, off);
        sq += __shfl_down(sq, off);
    }
    __shared__ float ps[4], pq[4];
    int wave = tid >> 6, lane = tid & 63;
    if (lane == 0) { ps[wave] = s; pq[wave] = sq; }
    __syncthreads();
    float ts = ps[0] + ps[1] + ps[2] + ps[3];
    float tq = pq[0] + pq[1] + pq[2] + pq[3];
    float mu  = ts * (1.f / (float)H);
    float var = tq * (1.f / (float)H) - mu * mu;
    float rstd = rsqrtf(var + 1e-8f);

    bf16x4_t ub = *reinterpret_cast<const bf16x4_t*>(&Ug[(size_t)row * 1024 + tid * 4]);
    float4 g  = *reinterpret_cast<const float4*>(&ln_g[tid * 4]);
    float4 bb = *reinterpret_cast<const float4*>(&ln_b[tid * 4]);
    float u0 = (float)ub[0], u1 = (float)ub[1], u2 = (float)ub[2], u3 = (float)ub[3];
    bf16x4_t outv;
    outv[0] = (__bf16)(((v0 - mu) * rstd * g.x + bb.x) * (u0 / (1.f + __expf(-u0))));
    outv[1] = (__bf16)(((v1 - mu) * rstd * g.y + bb.y) * (u1 / (1.f + __expf(-u1))));
    outv[2] = (__bf16)(((v2 - mu) * rstd * g.z + bb.z) * (u2 / (1.f + __expf(-u2))));
    outv[3] = (__bf16)(((v3 - mu) * rstd * g.w + bb.w) * (u3 / (1.f + __expf(-u3))));
    *reinterpret_cast<bf16x4_t*>(&gated[(size_t)row * H + tid * 4]) = outv;
}

// ---------------------------------------------------------------------------
extern "C" void kernel_launch(void* const* d_in, const int* in_sizes, int n_in,
                              void* d_out, int out_size, void* d_ws, size_t ws_size,
                              hipStream_t stream)
{
    const float* x    = (const float*)d_in[0];
    // d_in[1] = attn_mask: structurally causal tril; causality computed from indices.
    const float* Wp   = (const float*)d_in[2];
    const float* bp   = (const float*)d_in[3];
    const float* ln_g = (const float*)d_in[4];
    const float* ln_b = (const float*)d_in[5];
    const float* Wt   = (const float*)d_in[6];
    const float* bt   = (const float*)d_in[7];
    float* out = (float*)d_out;

    char* ws = (char*)d_ws;
    const size_t MB = 1024 * 1024;
    __bf16* Ug    = (__bf16*)(ws);              // 16 MB
    __bf16* Vh    = (__bf16*)(ws + 16  * MB);   // 16 MB
    __bf16* Qh    = (__bf16*)(ws + 32  * MB);   // 16 MB
    __bf16* Kh    = (__bf16*)(ws + 48  * MB);   // 16 MB
    __bf16* attn  = (__bf16*)(ws + 64  * MB);   // 16 MB
    __bf16* gated = (__bf16*)(ws + 80  * MB);   // 16 MB
    __bf16* VtG   = (__bf16*)(ws + 96  * MB);   // 16 MB
    __bf16* Ax    = (__bf16*)(ws + 112 * MB);   // 16 MB
    __bf16* Wp_t  = (__bf16*)(ws + 128 * MB);   //  8 MB
    __bf16* Wt_t  = (__bf16*)(ws + 136 * MB);   //  2 MB

    prep_kernel<<<13312, 256, 0, stream>>>(x, Wp, Wt, Ax, Wp_t, Wt_t);

    dim3 g1(4096 / 256, ROWS / 256);
    gemm_proj<<<g1, 512, 0, stream>>>(Ax, Wp_t, bp, Ug, Vh, Qh, Kh);

    transpose_v<<<dim3(S_ / 64, B_ * NH), 256, 0, stream>>>(Vh, VtG);

    attn_mfma<<<8 * B_ * NH, 512, 0, stream>>>(Qh, Kh, VtG, attn);

    ln_gate_kernel<<<ROWS, 256, 0, stream>>>(attn, Ug, ln_g, ln_b, gated);

    dim3 g3(1024 / 128, ROWS / 128);
    gemm_out<<<g3, 256, 0, stream>>>(gated, Wt_t, bt, x, out, ROWS, 1024, 1024);
}